// Round 1
// baseline (6001.506 us; speedup 1.0000x reference)
//
#include <hip/hip_runtime.h>
#include <math.h>

// GPPN: B=32, L_I=8, L_H=128, MAZE=64, F=5, OUT=16, k=10 (hard-coded: 9 LSTM steps)
// Internal state layout: [b][i][j][c] (c fastest). The reference's transposes are
// pure relabeling under this layout; all ops are per-pixel or spatial convs.

#define NB 32
#define HWD 64
#define CHN 128
#define NPIX (NB*HWD*HWD)          // 131072

// ---- workspace float offsets
#define OFF_W0   ((size_t)0)                    // hid, then h ping-pong A   (16777216 fl)
#define OFF_W1   ((size_t)16777216)             // h ping-pong B
#define OFF_CC   ((size_t)33554432)             // c (in-place)
#define OFF_SS   ((size_t)50331648)             // s field (131072 fl)
#define OFF_WT0  ((size_t)50462720)             // h0_w transposed [j][k][c]  (147456)
#define OFF_WT1  ((size_t)50610176)             // c0_w transposed
#define OFF_WHH  ((size_t)50757632)             // W_hh^T [k][cg]             (65536)
#define OFF_W5   ((size_t)50823168)             // conv_w transposed [j][k]   (3200)
#define OFF_BIAS ((size_t)50826368)             // b_ih + b_hh                (512)
#define WS_FLOATS ((size_t)50826880)

__device__ __forceinline__ float sigm(float x){ return 1.f/(1.f+__expf(-x)); }
__device__ __forceinline__ float tanhx(float x){ return 1.f - 2.f/(1.f+__expf(2.f*x)); }

// ---------------- weight transforms (one-time, coalesced-GEMM layouts) ------
__global__ void kTrans(const float* __restrict__ h0w, const float* __restrict__ c0w,
                       const float* __restrict__ whh, const float* __restrict__ cw5,
                       const float* __restrict__ bih, const float* __restrict__ bhh,
                       float* __restrict__ wt0, float* __restrict__ wt1,
                       float* __restrict__ whhT, float* __restrict__ w5t,
                       float* __restrict__ bsum)
{
    int e = blockIdx.x*256 + threadIdx.x;
    if (e < 147456) {
        int j = e >> 14;            // tap 0..8
        int k = (e >> 7) & 127;
        int c = e & 127;
        size_t src = (size_t)c*1152 + (size_t)k*9 + j;
        wt0[e] = h0w[src];
        wt1[e] = c0w[src];
    }
    if (e < 65536) { int k = e >> 9, cg = e & 511; whhT[e] = whh[(size_t)cg*128 + k]; }
    if (e < 3200)  { int j = e >> 7, k = e & 127;  w5t[e]  = cw5[(size_t)k*25 + j]; }
    if (e < 512)   { bsum[e] = bih[e] + bhh[e]; }
}

// ---------------- hid = conv3x3(X, hid_w) + hid_b ---------------------------
// grid: 32 * 16 * 16 (4x4 pixel tiles), 256 threads
__global__ __launch_bounds__(256) void kHid(const float* __restrict__ X,
                                            const float* __restrict__ hw,
                                            const float* __restrict__ hb,
                                            float* __restrict__ hid)
{
    __shared__ float Ws[128*73];     // stride 73 to break bank pattern
    __shared__ float Xs[6*6*8];
    int t = threadIdx.x;
    int blk = blockIdx.x;
    int b = blk >> 8, ti = (blk >> 4) & 15, tj = blk & 15;
    int i0 = ti*4, j0 = tj*4;
    for (int e = t; e < 9216; e += 256) {
        int c = e/72, q = e - c*72;
        Ws[c*73 + q] = hw[e];
    }
    for (int e = t; e < 288; e += 256) {
        int pos = e >> 3, ci = e & 7;
        int gi = i0 + pos/6 - 1, gj = j0 + pos%6 - 1;
        float v = 0.f;
        if ((unsigned)gi < 64u && (unsigned)gj < 64u)
            v = X[(((size_t)b*8 + ci)*64 + gi)*64 + gj];
        Xs[pos*8 + ci] = v;
    }
    __syncthreads();
    int c = t & 127, ph = t >> 7;
    float bv = hb[c];
    for (int p = ph*8; p < ph*8 + 8; ++p) {
        int pi = p >> 2, pj = p & 3;
        float acc = bv;
        #pragma unroll
        for (int ci = 0; ci < 8; ++ci)
            #pragma unroll
            for (int dy = 0; dy < 3; ++dy)
                #pragma unroll
                for (int dx = 0; dx < 3; ++dx)
                    acc += Xs[((pi+dy)*6 + (pj+dx))*8 + ci] * Ws[c*73 + ci*9 + dy*3 + dx];
        hid[(((size_t)b*64 + i0+pi)*64 + (j0+pj))*128 + c] = acc;
    }
}

// ---------------- 3x3 conv 128->128 (h0 / c0) -------------------------------
// grid: 32 * 8 * 8 (8x8 pixel tiles), 256 threads; thread = 4 pixels x 8 chans
__global__ __launch_bounds__(256,2) void kConv3(const float* __restrict__ src,
                                                const float* __restrict__ wt,   // [j][k][c]
                                                const float* __restrict__ bias,
                                                float* __restrict__ dst)
{
    __shared__ float sT[100*132];    // 10x10 halo tile, stride 132 (16B-aligned, 2-way banks)
    __shared__ float sW[32*128];
    int t = threadIdx.x;
    int blk = blockIdx.x;
    int b = blk >> 6, ti = (blk >> 3) & 7, tj = blk & 7;
    int i0 = ti*8, j0 = tj*8;
    for (int e = t; e < 6400; e += 256) {
        int pos = e >> 6, c2 = (e & 63)*2;
        int gi = i0 + pos/10 - 1, gj = j0 + pos%10 - 1;
        float2 v = make_float2(0.f, 0.f);
        if ((unsigned)gi < 64u && (unsigned)gj < 64u)
            v = *(const float2*)(src + (((size_t)b*64 + gi)*64 + gj)*128 + c2);
        *(float2*)(&sT[pos*132 + c2]) = v;
    }
    int pg = t & 15, c0 = (t >> 4)*8;
    float acc[4][8];
    #pragma unroll
    for (int q = 0; q < 4; ++q)
        #pragma unroll
        for (int e2 = 0; e2 < 8; ++e2) acc[q][e2] = 0.f;

    #pragma unroll 1
    for (int tap = 0; tap < 9; ++tap) {
        int dy = tap/3, dx = tap - dy*3;
        #pragma unroll 1
        for (int kc = 0; kc < 4; ++kc) {
            __syncthreads();
            for (int e = t; e < 4096; e += 256)
                sW[e] = wt[((size_t)tap*128 + kc*32 + (e >> 7))*128 + (e & 127)];
            __syncthreads();
            #pragma unroll
            for (int k4 = 0; k4 < 8; ++k4) {
                float4 hv[4];
                #pragma unroll
                for (int q = 0; q < 4; ++q) {
                    int p = pg + 16*q;
                    int pos = ((p >> 3) + dy)*10 + (p & 7) + dx;
                    hv[q] = *(const float4*)(&sT[pos*132 + kc*32 + k4*4]);
                }
                #pragma unroll
                for (int u = 0; u < 4; ++u) {
                    int kk = k4*4 + u;
                    float4 w0 = *(const float4*)(&sW[kk*128 + c0]);
                    float4 w1 = *(const float4*)(&sW[kk*128 + c0 + 4]);
                    #pragma unroll
                    for (int q = 0; q < 4; ++q) {
                        float h = (u==0)?hv[q].x:(u==1)?hv[q].y:(u==2)?hv[q].z:hv[q].w;
                        acc[q][0] += h*w0.x; acc[q][1] += h*w0.y;
                        acc[q][2] += h*w0.z; acc[q][3] += h*w0.w;
                        acc[q][4] += h*w1.x; acc[q][5] += h*w1.y;
                        acc[q][6] += h*w1.z; acc[q][7] += h*w1.w;
                    }
                }
            }
        }
    }
    float bv[8];
    #pragma unroll
    for (int e2 = 0; e2 < 8; ++e2) bv[e2] = bias[c0 + e2];
    #pragma unroll
    for (int q = 0; q < 4; ++q) {
        int p = pg + 16*q;
        int gi = i0 + (p >> 3), gj = j0 + (p & 7);
        float* o = dst + (((size_t)b*64 + gi)*64 + gj)*128 + c0;
        *(float4*)o     = make_float4(acc[q][0]+bv[0], acc[q][1]+bv[1], acc[q][2]+bv[2], acc[q][3]+bv[3]);
        *(float4*)(o+4) = make_float4(acc[q][4]+bv[4], acc[q][5]+bv[5], acc[q][6]+bv[6], acc[q][7]+bv[7]);
    }
}

// ---------------- s = conv5x5(h, conv_w) + conv_b ---------------------------
__global__ __launch_bounds__(256) void kConv5(const float* __restrict__ h,
                                              const float* __restrict__ w5t,  // [j][k]
                                              const float* __restrict__ cb,
                                              float* __restrict__ s)
{
    __shared__ float W5s[3200];
    int t = threadIdx.x;
    for (int e = t; e < 3200; e += 256) W5s[e] = w5t[e];
    __syncthreads();
    size_t pid = (size_t)blockIdx.x*256 + t;
    int b = (int)(pid >> 12), rem = (int)(pid & 4095);
    int i = rem >> 6, j = rem & 63;
    float acc = cb[0];
    #pragma unroll 1
    for (int j5 = 0; j5 < 25; ++j5) {
        int gi = i + j5/5 - 2, gj = j + j5%5 - 2;
        if ((unsigned)gi >= 64u || (unsigned)gj >= 64u) continue;
        const float4* hb4 = (const float4*)(h + (((size_t)b*64 + gi)*64 + gj)*128);
        const float4* wb4 = (const float4*)(&W5s[j5*128]);
        float sacc = 0.f;
        #pragma unroll
        for (int k4 = 0; k4 < 32; ++k4) {
            float4 hv = hb4[k4]; float4 wv = wb4[k4];
            sacc += hv.x*wv.x + hv.y*wv.y + hv.z*wv.z + hv.w*wv.w;
        }
        acc += sacc;
    }
    s[pid] = acc;
}

// ---------------- LSTM step: gates GEMM + pointwise -------------------------
// grid: NPIX/32 blocks, 256 threads; thread = 4 pixels x 4 chans x 4 gates
#define KCH 16
__global__ __launch_bounds__(256,2) void kStep(const float* __restrict__ hin,
                                               const float* __restrict__ whhT, // [k][cg]
                                               const float* __restrict__ s,
                                               const float* __restrict__ wih,
                                               const float* __restrict__ bsum,
                                               float* __restrict__ cc,
                                               float* __restrict__ hout)
{
    __shared__ float sH[32*132];
    __shared__ float sW[KCH*512];
    int t = threadIdx.x;
    size_t pid0 = (size_t)blockIdx.x * 32;
    for (int e = t; e < 1024; e += 256) {
        int p = e >> 5, c4 = (e & 31)*4;
        float4 v = *(const float4*)(hin + (pid0 + p)*128 + c4);
        *(float4*)(&sH[p*132 + c4]) = v;
    }
    int pg = t & 7, c0 = (t >> 3)*4;
    float acc[4][4][4];
    #pragma unroll
    for (int q = 0; q < 4; ++q)
        #pragma unroll
        for (int g = 0; g < 4; ++g)
            #pragma unroll
            for (int e2 = 0; e2 < 4; ++e2) acc[q][g][e2] = 0.f;

    #pragma unroll 1
    for (int kc = 0; kc < 8; ++kc) {
        __syncthreads();
        for (int e = t; e < KCH*128; e += 256) {       // float4 units
            int kk = e >> 7, c4 = (e & 127)*4;
            *(float4*)(&sW[kk*512 + c4]) = *(const float4*)(whhT + ((size_t)kc*KCH + kk)*512 + c4);
        }
        __syncthreads();
        #pragma unroll
        for (int kk = 0; kk < KCH; ++kk) {
            float4 w0 = *(const float4*)(&sW[kk*512 +   0 + c0]);
            float4 w1 = *(const float4*)(&sW[kk*512 + 128 + c0]);
            float4 w2 = *(const float4*)(&sW[kk*512 + 256 + c0]);
            float4 w3 = *(const float4*)(&sW[kk*512 + 384 + c0]);
            #pragma unroll
            for (int q = 0; q < 4; ++q) {
                float h = sH[(pg + 8*q)*132 + kc*KCH + kk];
                acc[q][0][0]+=h*w0.x; acc[q][0][1]+=h*w0.y; acc[q][0][2]+=h*w0.z; acc[q][0][3]+=h*w0.w;
                acc[q][1][0]+=h*w1.x; acc[q][1][1]+=h*w1.y; acc[q][1][2]+=h*w1.z; acc[q][1][3]+=h*w1.w;
                acc[q][2][0]+=h*w2.x; acc[q][2][1]+=h*w2.y; acc[q][2][2]+=h*w2.z; acc[q][2][3]+=h*w2.w;
                acc[q][3][0]+=h*w3.x; acc[q][3][1]+=h*w3.y; acc[q][3][2]+=h*w3.z; acc[q][3][3]+=h*w3.w;
            }
        }
    }
    float4 wv[4], bv[4];
    #pragma unroll
    for (int g = 0; g < 4; ++g) {
        wv[g] = *(const float4*)(wih  + g*128 + c0);
        bv[g] = *(const float4*)(bsum + g*128 + c0);
    }
    #pragma unroll
    for (int q = 0; q < 4; ++q) {
        size_t pix = pid0 + pg + 8*q;
        float sv = s[pix];
        float4 cold = *(const float4*)(cc + pix*128 + c0);
        const float* coldp = (const float*)&cold;
        float cn[4], hn[4];
        #pragma unroll
        for (int e2 = 0; e2 < 4; ++e2) {
            const float* w0p = (const float*)&wv[0]; const float* b0p = (const float*)&bv[0];
            const float* w1p = (const float*)&wv[1]; const float* b1p = (const float*)&bv[1];
            const float* w2p = (const float*)&wv[2]; const float* b2p = (const float*)&bv[2];
            const float* w3p = (const float*)&wv[3]; const float* b3p = (const float*)&bv[3];
            float vi = acc[q][0][e2] + sv*w0p[e2] + b0p[e2];
            float vf = acc[q][1][e2] + sv*w1p[e2] + b1p[e2];
            float vg = acc[q][2][e2] + sv*w2p[e2] + b2p[e2];
            float vo = acc[q][3][e2] + sv*w3p[e2] + b3p[e2];
            float cnew = sigm(vf)*coldp[e2] + sigm(vi)*tanhx(vg);
            cn[e2] = cnew;
            hn[e2] = sigm(vo)*tanhx(cnew);
        }
        *(float4*)(cc   + pix*128 + c0) = make_float4(cn[0],cn[1],cn[2],cn[3]);
        *(float4*)(hout + pix*128 + c0) = make_float4(hn[0],hn[1],hn[2],hn[3]);
    }
}

// ---------------- policy 1x1 conv ------------------------------------------
__global__ __launch_bounds__(256) void kPolicy(const float* __restrict__ h,
                                               const float* __restrict__ pw,
                                               float* __restrict__ out)
{
    __shared__ float Ps[16*128];
    int t = threadIdx.x;
    for (int e = t; e < 2048; e += 256) Ps[e] = pw[e];
    __syncthreads();
    size_t pid = (size_t)blockIdx.x*256 + t;
    int b = (int)(pid >> 12), rem = (int)(pid & 4095);
    float acc[16];
    #pragma unroll
    for (int o = 0; o < 16; ++o) acc[o] = 0.f;
    const float4* hb4 = (const float4*)(h + pid*128);
    #pragma unroll 4
    for (int k4 = 0; k4 < 32; ++k4) {
        float4 hv = hb4[k4];
        #pragma unroll
        for (int o = 0; o < 16; ++o) {
            float4 wv4 = *(const float4*)(&Ps[o*128 + k4*4]);
            acc[o] += hv.x*wv4.x + hv.y*wv4.y + hv.z*wv4.z + hv.w*wv4.w;
        }
    }
    #pragma unroll
    for (int o = 0; o < 16; ++o)
        out[((size_t)b*16 + o)*4096 + rem] = acc[o];
}

extern "C" void kernel_launch(void* const* d_in, const int* in_sizes, int n_in,
                              void* d_out, int out_size, void* d_ws, size_t ws_size,
                              hipStream_t stream) {
    const float* X      = (const float*)d_in[0];
    const float* hid_w  = (const float*)d_in[1];
    const float* hid_b  = (const float*)d_in[2];
    const float* h0_w   = (const float*)d_in[3];
    const float* h0_b   = (const float*)d_in[4];
    const float* c0_w   = (const float*)d_in[5];
    const float* c0_b   = (const float*)d_in[6];
    const float* conv_w = (const float*)d_in[7];
    const float* conv_b = (const float*)d_in[8];
    const float* W_ih   = (const float*)d_in[9];
    const float* W_hh   = (const float*)d_in[10];
    const float* b_ih   = (const float*)d_in[11];
    const float* b_hh   = (const float*)d_in[12];
    const float* pol_w  = (const float*)d_in[13];
    // d_in[14] = k (=10 on device); steps = k-1 = 9 hard-coded (host needs launch count)

    if (ws_size < WS_FLOATS*sizeof(float)) return;   // fail-visible guard

    float* ws   = (float*)d_ws;
    float* W0   = ws + OFF_W0;
    float* W1   = ws + OFF_W1;
    float* CC   = ws + OFF_CC;
    float* SS   = ws + OFF_SS;
    float* WT0  = ws + OFF_WT0;
    float* WT1  = ws + OFF_WT1;
    float* WHH  = ws + OFF_WHH;
    float* W5   = ws + OFF_W5;
    float* BS   = ws + OFF_BIAS;

    kTrans<<<576, 256, 0, stream>>>(h0_w, c0_w, W_hh, conv_w, b_ih, b_hh,
                                    WT0, WT1, WHH, W5, BS);
    kHid<<<8192, 256, 0, stream>>>(X, hid_w, hid_b, W0);
    kConv3<<<2048, 256, 0, stream>>>(W0, WT0, h0_b, W1);   // h0
    kConv3<<<2048, 256, 0, stream>>>(W0, WT1, c0_b, CC);   // c0
    for (int st = 0; st < 9; ++st) {
        const float* hin = (st & 1) ? W0 : W1;
        float* hout      = (st & 1) ? W1 : W0;
        kConv5<<<NPIX/256, 256, 0, stream>>>(hin, W5, conv_b, SS);
        kStep<<<NPIX/32, 256, 0, stream>>>(hin, WHH, SS, W_ih, BS, CC, hout);
    }
    kPolicy<<<NPIX/256, 256, 0, stream>>>(W0, pol_w, (float*)d_out);
}

// Round 2
// 2306.091 us; speedup vs baseline: 2.6025x; 2.6025x over previous
//
#include <hip/hip_runtime.h>
#include <math.h>

// GPPN fused: B=32, L_H=128, MAZE=64, F=5, OUT=16, k=10 (9 LSTM steps)
// State layout [pix][c]; h stored fp16, c fp32.
// conv5 factored as d = h @ W5^T (per-pixel GEMM), s[p] = sum_tap d[p+delta][tap].

typedef _Float16 f16;
typedef _Float16 f16x8 __attribute__((ext_vector_type(8)));
typedef float    f32x4 __attribute__((ext_vector_type(4)));

#define NB 32
#define HWD 64
#define NPIX (NB*HWD*HWD)   // 131072

// ---- workspace byte offsets
#define OB_HID   ((size_t)0)            // fp32 hid               64 MB
#define OB_CC    ((size_t)67108864)     // fp32 c                 64 MB
#define OB_HA    ((size_t)134217728)    // fp16 h ping            32 MB
#define OB_HB    ((size_t)167772160)    // fp16 h pong            32 MB
#define OB_WT0   ((size_t)201326592)    // f32 h0_w [tap][k][c]   589824 B
#define OB_WT1   ((size_t)201916416)    // f32 c0_w [tap][k][c]
#define OB_WGB   ((size_t)202506240)    // f16 W_hh B-frags       131072 B
#define OB_W5B   ((size_t)202637312)    // f16 W5 B-frags         8192 B
#define OB_BS    ((size_t)202645504)    // f32 b_ih+b_hh          2048 B
#define WS_BYTES ((size_t)202647552)

__device__ __forceinline__ float sigm(float x){ return 1.f/(1.f+__expf(-x)); }
__device__ __forceinline__ float tanhx(float x){ return 1.f - 2.f/(1.f+__expf(2.f*x)); }

// ---------------- one-time weight transforms --------------------------------
// WGB frag layout: value(fb, l, j) = W_hh[cg][k], fb=nt*4+kk, cg=nt*16+(l&15),
// k=kk*32+(l>>4)*8+j  -> lane l dwordx4-loads its whole B-fragment.
__global__ void kTrans(const float* __restrict__ h0w, const float* __restrict__ c0w,
                       const float* __restrict__ whh, const float* __restrict__ cw5,
                       const float* __restrict__ bih, const float* __restrict__ bhh,
                       float* __restrict__ wt0, float* __restrict__ wt1,
                       f16* __restrict__ wgb, f16* __restrict__ w5b,
                       float* __restrict__ bsum)
{
    int e = blockIdx.x*256 + threadIdx.x;
    if (e < 147456) {
        int j = e >> 14;            // tap 0..8
        int k = (e >> 7) & 127;
        int c = e & 127;
        size_t src = (size_t)c*1152 + (size_t)k*9 + j;
        wt0[e] = h0w[src];
        wt1[e] = c0w[src];
    }
    if (e < 65536) {
        int j = e & 7, l = (e >> 3) & 63, fb = e >> 9;
        int nt = fb >> 2, kk = fb & 3;
        int cg = nt*16 + (l & 15), k = kk*32 + (l >> 4)*8 + j;
        wgb[e] = (f16)whh[(size_t)cg*128 + k];
    }
    if (e < 4096) {
        int j = e & 7, l = (e >> 3) & 63, fb = e >> 9;
        int nt = fb >> 2, kk = fb & 3;
        int n = nt*16 + (l & 15), k = kk*32 + (l >> 4)*8 + j;
        w5b[e] = (n < 25) ? (f16)cw5[k*25 + n] : (f16)0.f;
    }
    if (e < 512) bsum[e] = bih[e] + bhh[e];
}

// ---------------- hid = conv3x3(X, hid_w) + hid_b (fp32, unchanged) ---------
__global__ __launch_bounds__(256) void kHid(const float* __restrict__ X,
                                            const float* __restrict__ hw,
                                            const float* __restrict__ hb,
                                            float* __restrict__ hid)
{
    __shared__ float Ws[128*73];
    __shared__ float Xs[6*6*8];
    int t = threadIdx.x;
    int blk = blockIdx.x;
    int b = blk >> 8, ti = (blk >> 4) & 15, tj = blk & 15;
    int i0 = ti*4, j0 = tj*4;
    for (int e = t; e < 9216; e += 256) {
        int c = e/72, q = e - c*72;
        Ws[c*73 + q] = hw[e];
    }
    for (int e = t; e < 288; e += 256) {
        int pos = e >> 3, ci = e & 7;
        int gi = i0 + pos/6 - 1, gj = j0 + pos%6 - 1;
        float v = 0.f;
        if ((unsigned)gi < 64u && (unsigned)gj < 64u)
            v = X[(((size_t)b*8 + ci)*64 + gi)*64 + gj];
        Xs[pos*8 + ci] = v;
    }
    __syncthreads();
    int c = t & 127, ph = t >> 7;
    float bv = hb[c];
    for (int p = ph*8; p < ph*8 + 8; ++p) {
        int pi = p >> 2, pj = p & 3;
        float acc = bv;
        #pragma unroll
        for (int ci = 0; ci < 8; ++ci)
            #pragma unroll
            for (int dy = 0; dy < 3; ++dy)
                #pragma unroll
                for (int dx = 0; dx < 3; ++dx)
                    acc += Xs[((pi+dy)*6 + (pj+dx))*8 + ci] * Ws[c*73 + ci*9 + dy*3 + dx];
        hid[(((size_t)b*64 + i0+pi)*64 + (j0+pj))*128 + c] = acc;
    }
}

// ---------------- 3x3 conv 128->128 (h0 fp16-out / c0 fp32-out) -------------
__global__ __launch_bounds__(256,2) void kConv3(const float* __restrict__ src,
                                                const float* __restrict__ wt,
                                                const float* __restrict__ bias,
                                                float* __restrict__ dst,
                                                f16* __restrict__ dst16)
{
    __shared__ float sT[100*132];
    __shared__ float sW[32*128];
    int t = threadIdx.x;
    int blk = blockIdx.x;
    int b = blk >> 6, ti = (blk >> 3) & 7, tj = blk & 7;
    int i0 = ti*8, j0 = tj*8;
    for (int e = t; e < 6400; e += 256) {
        int pos = e >> 6, c2 = (e & 63)*2;
        int gi = i0 + pos/10 - 1, gj = j0 + pos%10 - 1;
        float2 v = make_float2(0.f, 0.f);
        if ((unsigned)gi < 64u && (unsigned)gj < 64u)
            v = *(const float2*)(src + (((size_t)b*64 + gi)*64 + gj)*128 + c2);
        *(float2*)(&sT[pos*132 + c2]) = v;
    }
    int pg = t & 15, c0 = (t >> 4)*8;
    float acc[4][8];
    #pragma unroll
    for (int q = 0; q < 4; ++q)
        #pragma unroll
        for (int e2 = 0; e2 < 8; ++e2) acc[q][e2] = 0.f;

    #pragma unroll 1
    for (int tap = 0; tap < 9; ++tap) {
        int dy = tap/3, dx = tap - dy*3;
        #pragma unroll 1
        for (int kc = 0; kc < 4; ++kc) {
            __syncthreads();
            for (int e = t; e < 4096; e += 256)
                sW[e] = wt[((size_t)tap*128 + kc*32 + (e >> 7))*128 + (e & 127)];
            __syncthreads();
            #pragma unroll
            for (int k4 = 0; k4 < 8; ++k4) {
                float4 hv[4];
                #pragma unroll
                for (int q = 0; q < 4; ++q) {
                    int p = pg + 16*q;
                    int pos = ((p >> 3) + dy)*10 + (p & 7) + dx;
                    hv[q] = *(const float4*)(&sT[pos*132 + kc*32 + k4*4]);
                }
                #pragma unroll
                for (int u = 0; u < 4; ++u) {
                    int kk = k4*4 + u;
                    float4 w0 = *(const float4*)(&sW[kk*128 + c0]);
                    float4 w1 = *(const float4*)(&sW[kk*128 + c0 + 4]);
                    #pragma unroll
                    for (int q = 0; q < 4; ++q) {
                        float h = (u==0)?hv[q].x:(u==1)?hv[q].y:(u==2)?hv[q].z:hv[q].w;
                        acc[q][0] += h*w0.x; acc[q][1] += h*w0.y;
                        acc[q][2] += h*w0.z; acc[q][3] += h*w0.w;
                        acc[q][4] += h*w1.x; acc[q][5] += h*w1.y;
                        acc[q][6] += h*w1.z; acc[q][7] += h*w1.w;
                    }
                }
            }
        }
    }
    float bv[8];
    #pragma unroll
    for (int e2 = 0; e2 < 8; ++e2) bv[e2] = bias[c0 + e2];
    #pragma unroll
    for (int q = 0; q < 4; ++q) {
        int p = pg + 16*q;
        int gi = i0 + (p >> 3), gj = j0 + (p & 7);
        size_t base = (((size_t)b*64 + gi)*64 + gj)*128 + c0;
        if (dst16) {
            f16x8 hv;
            #pragma unroll
            for (int e2 = 0; e2 < 8; ++e2) hv[e2] = (f16)(acc[q][e2] + bv[e2]);
            *(f16x8*)(dst16 + base) = hv;
        } else {
            *(float4*)(dst + base)     = make_float4(acc[q][0]+bv[0], acc[q][1]+bv[1], acc[q][2]+bv[2], acc[q][3]+bv[3]);
            *(float4*)(dst + base + 4) = make_float4(acc[q][4]+bv[4], acc[q][5]+bv[5], acc[q][6]+bv[6], acc[q][7]+bv[7]);
        }
    }
}

// ---------------- fused LSTM step: conv5(d-GEMM+gather) + gates MFMA + pointwise
// block = 8x8 pixel tile, 256 threads = 4 waves.
// wave w: wn=w>>1 selects c-quarter, wm=w&1 selects M-tile pair {wm, wm+2}.
__global__ __launch_bounds__(256,2) void kFuse(const f16* __restrict__ hin,
                                               const f16* __restrict__ wgb,
                                               const f16* __restrict__ w5b,
                                               const float* __restrict__ wih,
                                               const float* __restrict__ bsum,
                                               const float* __restrict__ cb,
                                               float* __restrict__ cc,
                                               f16* __restrict__ hout)
{
    __shared__ f16   sHalo[144*128];   // 36864 B, 16B-chunk XOR-swizzled
    __shared__ float sD[144*32];       // 18432 B
    __shared__ float sS[64];
    int t = threadIdx.x;
    int blk = blockIdx.x;
    int b = blk >> 6, ti = (blk >> 3) & 7, tj = blk & 7;
    int i0 = ti*8, j0 = tj*8;
    int l = t & 63, w = t >> 6;

    // ---- stage 12x12 halo (fp16, zero-padded), swizzle chunk ^= pos&7
    for (int e = t; e < 2304; e += 256) {
        int pos = e >> 4, ch = e & 15;
        int gi = i0 + pos/12 - 2, gj = j0 + pos%12 - 2;
        f16x8 v = {0,0,0,0,0,0,0,0};
        if ((unsigned)gi < 64u && (unsigned)gj < 64u)
            v = *(const f16x8*)(hin + ((((size_t)b*64 + gi)*64 + gj)*128) + ch*8);
        *(f16x8*)&sHalo[(pos*16 + (ch ^ (pos & 7)))*8] = v;
    }
    __syncthreads();

    // ---- d-GEMM: d[pos][tap] = h_halo[pos] . w5[tap]   (144 x 32 x K=128)
    for (int mt = w; mt < 9; mt += 4) {
        int row = mt*16 + (l & 15);
        f16x8 a[4];
        #pragma unroll
        for (int kk = 0; kk < 4; ++kk)
            a[kk] = *(const f16x8*)&sHalo[(row*16 + ((kk*4 + (l >> 4)) ^ (row & 7)))*8];
        #pragma unroll
        for (int nt = 0; nt < 2; ++nt) {
            f32x4 c = {0.f,0.f,0.f,0.f};
            #pragma unroll
            for (int kk = 0; kk < 4; ++kk) {
                f16x8 bf = *(const f16x8*)(w5b + ((size_t)((nt*4 + kk)*64 + l))*8);
                c = __builtin_amdgcn_mfma_f32_16x16x32_f16(a[kk], bf, c, 0, 0, 0);
            }
            #pragma unroll
            for (int r = 0; r < 4; ++r)
                sD[(mt*16 + (l >> 4)*4 + r)*32 + nt*16 + (l & 15)] = c[r];
        }
    }
    __syncthreads();

    // ---- s[p] = conv_b + sum_{tap<25} d[p+delta(tap)][tap]
    {
        int p = t >> 2, sub = t & 3;
        int pi = p >> 3, pj = p & 7;
        float acc = 0.f;
        for (int tap = sub; tap < 25; tap += 4) {
            int ty = tap/5, tx = tap - ty*5;
            acc += sD[((pi + ty)*12 + (pj + tx))*32 + tap];
        }
        acc += __shfl_xor(acc, 1);
        acc += __shfl_xor(acc, 2);
        if (sub == 0) sS[p] = acc + cb[0];
    }
    __syncthreads();

    // ---- gates GEMM: [64 pix] x [512 cg], K=128. nt(g,q) = g*8 + wn*4 + q
    int wn = w >> 1, wm = w & 1;
    f16x8 a[2][4];
    #pragma unroll
    for (int mi = 0; mi < 2; ++mi) {
        int mrow = (wm + mi*2)*16 + (l & 15);
        int hpos = ((mrow >> 3) + 2)*12 + (mrow & 7) + 2;
        #pragma unroll
        for (int kk = 0; kk < 4; ++kk)
            a[mi][kk] = *(const f16x8*)&sHalo[(hpos*16 + ((kk*4 + (l >> 4)) ^ (hpos & 7)))*8];
    }
    f32x4 acc[2][4][4];   // [mi][q][gate]
    #pragma unroll
    for (int mi = 0; mi < 2; ++mi)
        #pragma unroll
        for (int q = 0; q < 4; ++q)
            #pragma unroll
            for (int g = 0; g < 4; ++g)
                acc[mi][q][g] = (f32x4){0.f,0.f,0.f,0.f};

    #pragma unroll
    for (int q = 0; q < 4; ++q) {
        #pragma unroll
        for (int g = 0; g < 4; ++g) {
            int nt = g*8 + wn*4 + q;
            f16x8 bf[4];
            #pragma unroll
            for (int kk = 0; kk < 4; ++kk)
                bf[kk] = *(const f16x8*)(wgb + ((size_t)((nt*4 + kk)*64 + l))*8);
            #pragma unroll
            for (int mi = 0; mi < 2; ++mi)
                #pragma unroll
                for (int kk = 0; kk < 4; ++kk)
                    acc[mi][q][g] = __builtin_amdgcn_mfma_f32_16x16x32_f16(a[mi][kk], bf[kk], acc[mi][q][g], 0, 0, 0);
        }
    }

    // ---- epilogue: gates + LSTM pointwise (all lane-local)
    int cl = l & 15;
    #pragma unroll
    for (int mi = 0; mi < 2; ++mi) {
        #pragma unroll
        for (int q = 0; q < 4; ++q) {
            int c = (wn*4 + q)*16 + cl;
            float wii = wih[c], wif = wih[128+c], wig = wih[256+c], wio = wih[384+c];
            float bi = bsum[c], bf = bsum[128+c], bg = bsum[256+c], bo = bsum[384+c];
            #pragma unroll
            for (int r = 0; r < 4; ++r) {
                int m = (wm + mi*2)*16 + (l >> 4)*4 + r;
                float sv = sS[m];
                size_t gp = ((((size_t)b*64 + i0 + (m >> 3))*64 + j0 + (m & 7))*128) + c;
                float cold = cc[gp];
                float vi = acc[mi][q][0][r] + sv*wii + bi;
                float vf = acc[mi][q][1][r] + sv*wif + bf;
                float vg = acc[mi][q][2][r] + sv*wig + bg;
                float vo = acc[mi][q][3][r] + sv*wio + bo;
                float cn = sigm(vf)*cold + sigm(vi)*tanhx(vg);
                cc[gp] = cn;
                hout[gp] = (f16)(sigm(vo)*tanhx(cn));
            }
        }
    }
}

// ---------------- policy 1x1 conv (fp16 h in, fp32 out) ---------------------
__global__ __launch_bounds__(256) void kPolicy(const f16* __restrict__ h,
                                               const float* __restrict__ pw,
                                               float* __restrict__ out)
{
    __shared__ float Ps[16*128];
    int t = threadIdx.x;
    for (int e = t; e < 2048; e += 256) Ps[e] = pw[e];
    __syncthreads();
    size_t pid = (size_t)blockIdx.x*256 + t;
    int b = (int)(pid >> 12), rem = (int)(pid & 4095);
    float acc[16];
    #pragma unroll
    for (int o = 0; o < 16; ++o) acc[o] = 0.f;
    const f16x8* hb8 = (const f16x8*)(h + pid*128);
    #pragma unroll 2
    for (int k8 = 0; k8 < 16; ++k8) {
        f16x8 hv = hb8[k8];
        float hf[8];
        #pragma unroll
        for (int e = 0; e < 8; ++e) hf[e] = (float)hv[e];
        #pragma unroll
        for (int o = 0; o < 16; ++o) {
            float4 w0 = *(const float4*)&Ps[o*128 + k8*8];
            float4 w1 = *(const float4*)&Ps[o*128 + k8*8 + 4];
            acc[o] += hf[0]*w0.x + hf[1]*w0.y + hf[2]*w0.z + hf[3]*w0.w
                    + hf[4]*w1.x + hf[5]*w1.y + hf[6]*w1.z + hf[7]*w1.w;
        }
    }
    #pragma unroll
    for (int o = 0; o < 16; ++o)
        out[((size_t)b*16 + o)*4096 + rem] = acc[o];
}

extern "C" void kernel_launch(void* const* d_in, const int* in_sizes, int n_in,
                              void* d_out, int out_size, void* d_ws, size_t ws_size,
                              hipStream_t stream) {
    const float* X      = (const float*)d_in[0];
    const float* hid_w  = (const float*)d_in[1];
    const float* hid_b  = (const float*)d_in[2];
    const float* h0_w   = (const float*)d_in[3];
    const float* h0_b   = (const float*)d_in[4];
    const float* c0_w   = (const float*)d_in[5];
    const float* c0_b   = (const float*)d_in[6];
    const float* conv_w = (const float*)d_in[7];
    const float* conv_b = (const float*)d_in[8];
    const float* W_ih   = (const float*)d_in[9];
    const float* W_hh   = (const float*)d_in[10];
    const float* b_ih   = (const float*)d_in[11];
    const float* b_hh   = (const float*)d_in[12];
    const float* pol_w  = (const float*)d_in[13];
    // d_in[14] = k (=10); steps = k-1 = 9 hard-coded

    if (ws_size < WS_BYTES) return;   // fail-visible guard

    char* wsb = (char*)d_ws;
    float* HID = (float*)(wsb + OB_HID);
    float* CC  = (float*)(wsb + OB_CC);
    f16*   HA  = (f16*)  (wsb + OB_HA);
    f16*   HB  = (f16*)  (wsb + OB_HB);
    float* WT0 = (float*)(wsb + OB_WT0);
    float* WT1 = (float*)(wsb + OB_WT1);
    f16*   WGB = (f16*)  (wsb + OB_WGB);
    f16*   W5B = (f16*)  (wsb + OB_W5B);
    float* BS  = (float*)(wsb + OB_BS);

    kTrans<<<576, 256, 0, stream>>>(h0_w, c0_w, W_hh, conv_w, b_ih, b_hh,
                                    WT0, WT1, WGB, W5B, BS);
    kHid<<<8192, 256, 0, stream>>>(X, hid_w, hid_b, HID);
    kConv3<<<2048, 256, 0, stream>>>(HID, WT0, h0_b, nullptr, HA);  // h0 -> fp16
    kConv3<<<2048, 256, 0, stream>>>(HID, WT1, c0_b, CC, nullptr);  // c0 -> fp32
    for (int st = 0; st < 9; ++st) {
        const f16* hin = (st & 1) ? HB : HA;
        f16* hout      = (st & 1) ? HA : HB;
        kFuse<<<2048, 256, 0, stream>>>(hin, WGB, W5B, W_ih, BS, conv_b, CC, hout);
    }
    kPolicy<<<512, 256, 0, stream>>>(HB, pol_w, (float*)d_out);
}

// Round 4
// 1045.328 us; speedup vs baseline: 5.7413x; 2.2061x over previous
//
#include <hip/hip_runtime.h>
#include <math.h>

// GPPN fused: B=32, L_H=128, MAZE=64, F=5, OUT=16, k=10 (9 LSTM steps)
// State layout [pix][c]; hid & h stored fp16, c fp32.
// conv5 factored as d = h @ W5^T (per-pixel GEMM), s[p] = sum_tap d[p+delta][tap].
// h0/c0 3x3 convs fused into one 9-tap MFMA GEMM (N=256 = h0||c0).

typedef _Float16 f16;
typedef _Float16 f16x8 __attribute__((ext_vector_type(8)));
typedef float    f32x4 __attribute__((ext_vector_type(4)));

#define NB 32
#define HWD 64
#define NPIX (NB*HWD*HWD)   // 131072

// ---- workspace byte offsets
#define OB_HID   ((size_t)0)            // fp16 hid               32 MB
#define OB_CC    ((size_t)33554432)     // fp32 c                 64 MB
#define OB_HA    ((size_t)100663296)    // fp16 h ping            32 MB
#define OB_HB    ((size_t)134217728)    // fp16 h pong            32 MB
#define OB_WCB   ((size_t)167772160)    // f16 conv3 B-frags [tap][nt16][kk][l][8]  589824 B
#define OB_WGB   ((size_t)168361984)    // f16 W_hh B-frags       131072 B
#define OB_W5B   ((size_t)168493056)    // f16 W5 B-frags         8192 B
#define OB_BS    ((size_t)168501248)    // f32 b_ih+b_hh          2048 B
#define WS_BYTES ((size_t)168503296)

__device__ __forceinline__ float sigm(float x){ return 1.f/(1.f+__expf(-x)); }
__device__ __forceinline__ float tanhx(float x){ return 1.f - 2.f/(1.f+__expf(2.f*x)); }

// ---------------- one-time weight transforms --------------------------------
// Frag layout (all B-mats): value(frag fb, lane l, j) = W[n][k],
//   n = nt*16 + (l&15), k = kk*32 + (l>>4)*8 + j  -> lane dwordx4-loads its frag.
__global__ void kTrans(const float* __restrict__ h0w, const float* __restrict__ c0w,
                       const float* __restrict__ whh, const float* __restrict__ cw5,
                       const float* __restrict__ bih, const float* __restrict__ bhh,
                       f16* __restrict__ wcb, f16* __restrict__ wgb,
                       f16* __restrict__ w5b, float* __restrict__ bsum)
{
    int e = blockIdx.x*256 + threadIdx.x;
    if (e < 294912) {                    // conv3 frags: [tap][nt(16)][kk(4)] ; nt<8 h0, nt>=8 c0
        int j = e & 7, l = (e >> 3) & 63, kk = (e >> 9) & 3;
        int nt = (e >> 11) & 15, tap = e >> 15;
        int c = (nt & 7)*16 + (l & 15);
        int k = kk*32 + (l >> 4)*8 + j;
        const float* src = (nt < 8) ? h0w : c0w;
        wcb[e] = (f16)src[((size_t)c*128 + k)*9 + tap];
    }
    if (e < 65536) {
        int j = e & 7, l = (e >> 3) & 63, fb = e >> 9;
        int nt = fb >> 2, kk = fb & 3;
        int cg = nt*16 + (l & 15), k = kk*32 + (l >> 4)*8 + j;
        wgb[e] = (f16)whh[(size_t)cg*128 + k];
    }
    if (e < 4096) {
        int j = e & 7, l = (e >> 3) & 63, fb = e >> 9;
        int nt = fb >> 2, kk = fb & 3;
        int n = nt*16 + (l & 15), k = kk*32 + (l >> 4)*8 + j;
        w5b[e] = (n < 25) ? (f16)cw5[k*25 + n] : (f16)0.f;
    }
    if (e < 512) bsum[e] = bih[e] + bhh[e];
}

// ---------------- hid = conv3x3(X, hid_w) + hid_b (fp32 math, fp16 out) -----
__global__ __launch_bounds__(256) void kHid(const float* __restrict__ X,
                                            const float* __restrict__ hw,
                                            const float* __restrict__ hb,
                                            f16* __restrict__ hid)
{
    __shared__ float Ws[128*73];
    __shared__ float Xs[6*6*8];
    int t = threadIdx.x;
    int blk = blockIdx.x;
    int b = blk >> 8, ti = (blk >> 4) & 15, tj = blk & 15;
    int i0 = ti*4, j0 = tj*4;
    for (int e = t; e < 9216; e += 256) {
        int c = e/72, q = e - c*72;
        Ws[c*73 + q] = hw[e];
    }
    for (int e = t; e < 288; e += 256) {
        int pos = e >> 3, ci = e & 7;
        int gi = i0 + pos/6 - 1, gj = j0 + pos%6 - 1;
        float v = 0.f;
        if ((unsigned)gi < 64u && (unsigned)gj < 64u)
            v = X[(((size_t)b*8 + ci)*64 + gi)*64 + gj];
        Xs[pos*8 + ci] = v;
    }
    __syncthreads();
    int c = t & 127, ph = t >> 7;
    float bv = hb[c];
    for (int p = ph*8; p < ph*8 + 8; ++p) {
        int pi = p >> 2, pj = p & 3;
        float acc = bv;
        #pragma unroll
        for (int ci = 0; ci < 8; ++ci)
            #pragma unroll
            for (int dy = 0; dy < 3; ++dy)
                #pragma unroll
                for (int dx = 0; dx < 3; ++dx)
                    acc += Xs[((pi+dy)*6 + (pj+dx))*8 + ci] * Ws[c*73 + ci*9 + dy*3 + dx];
        hid[(((size_t)b*64 + i0+pi)*64 + (j0+pj))*128 + c] = (f16)acc;
    }
}

// ---------------- h0 & c0: 9-tap MFMA GEMM, M=64 pix, N=256 (h0||c0), K=128/tap
// block = 8x8 pixel tile, 256 threads = 4 waves; wave wn owns nt = wn*4..wn*4+3.
// waves 0/1 -> h0 (fp16), waves 2/3 -> c0 (fp32).
__global__ __launch_bounds__(256,2) void kInit(const f16* __restrict__ hid,
                                               const f16* __restrict__ wcb,
                                               const float* __restrict__ h0b,
                                               const float* __restrict__ c0b,
                                               f16* __restrict__ h0out,
                                               float* __restrict__ c0out)
{
    __shared__ f16 sHalo[100*128];   // 10x10 halo, 25600 B, 16B-chunk XOR-swizzled
    int t = threadIdx.x;
    int blk = blockIdx.x;
    int b = blk >> 6, ti = (blk >> 3) & 7, tj = blk & 7;
    int i0 = ti*8, j0 = tj*8;
    int l = t & 63, wn = t >> 6;

    for (int e = t; e < 1600; e += 256) {
        int pos = e >> 4, ch = e & 15;
        int gi = i0 + pos/10 - 1, gj = j0 + pos%10 - 1;
        f16x8 v = {0,0,0,0,0,0,0,0};
        if ((unsigned)gi < 64u && (unsigned)gj < 64u)
            v = *(const f16x8*)(hid + ((((size_t)b*64 + gi)*64 + gj)*128) + ch*8);
        *(f16x8*)&sHalo[(pos*16 + (ch ^ (pos & 7)))*8] = v;
    }
    __syncthreads();

    f32x4 acc[4][4];   // [mi][q]
    #pragma unroll
    for (int mi = 0; mi < 4; ++mi)
        #pragma unroll
        for (int q = 0; q < 4; ++q) acc[mi][q] = (f32x4){0.f,0.f,0.f,0.f};

    for (int tap = 0; tap < 9; ++tap) {
        int dy = tap/3, dx = tap - dy*3;
        f16x8 a[4][4];
        #pragma unroll
        for (int mi = 0; mi < 4; ++mi) {
            int mrow = mi*16 + (l & 15);
            int pos = ((mrow >> 3) + dy)*10 + (mrow & 7) + dx;
            #pragma unroll
            for (int kk = 0; kk < 4; ++kk)
                a[mi][kk] = *(const f16x8*)&sHalo[(pos*16 + ((kk*4 + (l >> 4)) ^ (pos & 7)))*8];
        }
        #pragma unroll
        for (int q = 0; q < 4; ++q) {
            int nt = wn*4 + q;
            f16x8 bf[4];
            #pragma unroll
            for (int kk = 0; kk < 4; ++kk)
                bf[kk] = *(const f16x8*)(wcb + ((size_t)((tap*16 + nt)*4 + kk)*64 + l)*8);
            #pragma unroll
            for (int mi = 0; mi < 4; ++mi)
                #pragma unroll
                for (int kk = 0; kk < 4; ++kk)
                    acc[mi][q] = __builtin_amdgcn_mfma_f32_16x16x32_f16(a[mi][kk], bf[kk], acc[mi][q], 0, 0, 0);
        }
    }

    // epilogue: wave-uniform split h0 (fp16) vs c0 (fp32)
    int cl = l & 15;
    bool isC = (wn >= 2);
    #pragma unroll
    for (int q = 0; q < 4; ++q) {
        int c = ((wn & 1)*4 + q)*16 + cl;
        float bv = isC ? c0b[c] : h0b[c];
        #pragma unroll
        for (int mi = 0; mi < 4; ++mi) {
            #pragma unroll
            for (int r = 0; r < 4; ++r) {
                int m = mi*16 + (l >> 4)*4 + r;
                size_t gp = ((((size_t)b*64 + i0 + (m >> 3))*64 + j0 + (m & 7))*128) + c;
                float v = acc[mi][q][r] + bv;
                if (isC) c0out[gp] = v;
                else     h0out[gp] = (f16)v;
            }
        }
    }
}

// ---------------- fused LSTM step (unchanged from R2) -----------------------
__global__ __launch_bounds__(256,2) void kFuse(const f16* __restrict__ hin,
                                               const f16* __restrict__ wgb,
                                               const f16* __restrict__ w5b,
                                               const float* __restrict__ wih,
                                               const float* __restrict__ bsum,
                                               const float* __restrict__ cb,
                                               float* __restrict__ cc,
                                               f16* __restrict__ hout)
{
    __shared__ f16   sHalo[144*128];   // 36864 B, 16B-chunk XOR-swizzled
    __shared__ float sD[144*32];       // 18432 B
    __shared__ float sS[64];
    int t = threadIdx.x;
    int blk = blockIdx.x;
    int b = blk >> 6, ti = (blk >> 3) & 7, tj = blk & 7;
    int i0 = ti*8, j0 = tj*8;
    int l = t & 63, w = t >> 6;

    for (int e = t; e < 2304; e += 256) {
        int pos = e >> 4, ch = e & 15;
        int gi = i0 + pos/12 - 2, gj = j0 + pos%12 - 2;
        f16x8 v = {0,0,0,0,0,0,0,0};
        if ((unsigned)gi < 64u && (unsigned)gj < 64u)
            v = *(const f16x8*)(hin + ((((size_t)b*64 + gi)*64 + gj)*128) + ch*8);
        *(f16x8*)&sHalo[(pos*16 + (ch ^ (pos & 7)))*8] = v;
    }
    __syncthreads();

    // d-GEMM: d[pos][tap] = h_halo[pos] . w5[tap]   (144 x 32 x K=128)
    for (int mt = w; mt < 9; mt += 4) {
        int row = mt*16 + (l & 15);
        f16x8 a[4];
        #pragma unroll
        for (int kk = 0; kk < 4; ++kk)
            a[kk] = *(const f16x8*)&sHalo[(row*16 + ((kk*4 + (l >> 4)) ^ (row & 7)))*8];
        #pragma unroll
        for (int nt = 0; nt < 2; ++nt) {
            f32x4 c = {0.f,0.f,0.f,0.f};
            #pragma unroll
            for (int kk = 0; kk < 4; ++kk) {
                f16x8 bf = *(const f16x8*)(w5b + ((size_t)((nt*4 + kk)*64 + l))*8);
                c = __builtin_amdgcn_mfma_f32_16x16x32_f16(a[kk], bf, c, 0, 0, 0);
            }
            #pragma unroll
            for (int r = 0; r < 4; ++r)
                sD[(mt*16 + (l >> 4)*4 + r)*32 + nt*16 + (l & 15)] = c[r];
        }
    }
    __syncthreads();

    // s[p] = conv_b + sum_{tap<25} d[p+delta(tap)][tap]
    {
        int p = t >> 2, sub = t & 3;
        int pi = p >> 3, pj = p & 7;
        float acc = 0.f;
        for (int tap = sub; tap < 25; tap += 4) {
            int ty = tap/5, tx = tap - ty*5;
            acc += sD[((pi + ty)*12 + (pj + tx))*32 + tap];
        }
        acc += __shfl_xor(acc, 1);
        acc += __shfl_xor(acc, 2);
        if (sub == 0) sS[p] = acc + cb[0];
    }
    __syncthreads();

    // gates GEMM: [64 pix] x [512 cg], K=128. nt(g,q) = g*8 + wn*4 + q
    int wn = w >> 1, wm = w & 1;
    f16x8 a[2][4];
    #pragma unroll
    for (int mi = 0; mi < 2; ++mi) {
        int mrow = (wm + mi*2)*16 + (l & 15);
        int hpos = ((mrow >> 3) + 2)*12 + (mrow & 7) + 2;
        #pragma unroll
        for (int kk = 0; kk < 4; ++kk)
            a[mi][kk] = *(const f16x8*)&sHalo[(hpos*16 + ((kk*4 + (l >> 4)) ^ (hpos & 7)))*8];
    }
    f32x4 acc[2][4][4];   // [mi][q][gate]
    #pragma unroll
    for (int mi = 0; mi < 2; ++mi)
        #pragma unroll
        for (int q = 0; q < 4; ++q)
            #pragma unroll
            for (int g = 0; g < 4; ++g)
                acc[mi][q][g] = (f32x4){0.f,0.f,0.f,0.f};

    #pragma unroll
    for (int q = 0; q < 4; ++q) {
        #pragma unroll
        for (int g = 0; g < 4; ++g) {
            int nt = g*8 + wn*4 + q;
            f16x8 bf[4];
            #pragma unroll
            for (int kk = 0; kk < 4; ++kk)
                bf[kk] = *(const f16x8*)(wgb + ((size_t)((nt*4 + kk)*64 + l))*8);
            #pragma unroll
            for (int mi = 0; mi < 2; ++mi)
                #pragma unroll
                for (int kk = 0; kk < 4; ++kk)
                    acc[mi][q][g] = __builtin_amdgcn_mfma_f32_16x16x32_f16(a[mi][kk], bf[kk], acc[mi][q][g], 0, 0, 0);
        }
    }

    // epilogue: gates + LSTM pointwise (all lane-local)
    int cl = l & 15;
    #pragma unroll
    for (int mi = 0; mi < 2; ++mi) {
        #pragma unroll
        for (int q = 0; q < 4; ++q) {
            int c = (wn*4 + q)*16 + cl;
            float wii = wih[c], wif = wih[128+c], wig = wih[256+c], wio = wih[384+c];
            float bi = bsum[c], bf = bsum[128+c], bg = bsum[256+c], bo = bsum[384+c];
            #pragma unroll
            for (int r = 0; r < 4; ++r) {
                int m = (wm + mi*2)*16 + (l >> 4)*4 + r;
                float sv = sS[m];
                size_t gp = ((((size_t)b*64 + i0 + (m >> 3))*64 + j0 + (m & 7))*128) + c;
                float cold = cc[gp];
                float vi = acc[mi][q][0][r] + sv*wii + bi;
                float vf = acc[mi][q][1][r] + sv*wif + bf;
                float vg = acc[mi][q][2][r] + sv*wig + bg;
                float vo = acc[mi][q][3][r] + sv*wio + bo;
                float cn = sigm(vf)*cold + sigm(vi)*tanhx(vg);
                cc[gp] = cn;
                hout[gp] = (f16)(sigm(vo)*tanhx(cn));
            }
        }
    }
}

// ---------------- policy 1x1 conv (fp16 h in, fp32 out) ---------------------
__global__ __launch_bounds__(256) void kPolicy(const f16* __restrict__ h,
                                               const float* __restrict__ pw,
                                               float* __restrict__ out)
{
    __shared__ float Ps[16*128];
    int t = threadIdx.x;
    for (int e = t; e < 2048; e += 256) Ps[e] = pw[e];
    __syncthreads();
    size_t pid = (size_t)blockIdx.x*256 + t;
    int b = (int)(pid >> 12), rem = (int)(pid & 4095);
    float acc[16];
    #pragma unroll
    for (int o = 0; o < 16; ++o) acc[o] = 0.f;
    const f16x8* hb8 = (const f16x8*)(h + pid*128);
    #pragma unroll 2
    for (int k8 = 0; k8 < 16; ++k8) {
        f16x8 hv = hb8[k8];
        float hf[8];
        #pragma unroll
        for (int e = 0; e < 8; ++e) hf[e] = (float)hv[e];
        #pragma unroll
        for (int o = 0; o < 16; ++o) {
            float4 w0 = *(const float4*)&Ps[o*128 + k8*8];
            float4 w1 = *(const float4*)&Ps[o*128 + k8*8 + 4];
            acc[o] += hf[0]*w0.x + hf[1]*w0.y + hf[2]*w0.z + hf[3]*w0.w
                    + hf[4]*w1.x + hf[5]*w1.y + hf[6]*w1.z + hf[7]*w1.w;
        }
    }
    #pragma unroll
    for (int o = 0; o < 16; ++o)
        out[((size_t)b*16 + o)*4096 + rem] = acc[o];
}

extern "C" void kernel_launch(void* const* d_in, const int* in_sizes, int n_in,
                              void* d_out, int out_size, void* d_ws, size_t ws_size,
                              hipStream_t stream) {
    const float* X      = (const float*)d_in[0];
    const float* hid_w  = (const float*)d_in[1];
    const float* hid_b  = (const float*)d_in[2];
    const float* h0_w   = (const float*)d_in[3];
    const float* h0_b   = (const float*)d_in[4];
    const float* c0_w   = (const float*)d_in[5];
    const float* c0_b   = (const float*)d_in[6];
    const float* conv_w = (const float*)d_in[7];
    const float* conv_b = (const float*)d_in[8];
    const float* W_ih   = (const float*)d_in[9];
    const float* W_hh   = (const float*)d_in[10];
    const float* b_ih   = (const float*)d_in[11];
    const float* b_hh   = (const float*)d_in[12];
    const float* pol_w  = (const float*)d_in[13];
    // d_in[14] = k (=10); steps = k-1 = 9 hard-coded

    if (ws_size < WS_BYTES) return;   // fail-visible guard

    char* wsb = (char*)d_ws;
    f16*   HID = (f16*)  (wsb + OB_HID);
    float* CC  = (float*)(wsb + OB_CC);
    f16*   HA  = (f16*)  (wsb + OB_HA);
    f16*   HB  = (f16*)  (wsb + OB_HB);
    f16*   WCB = (f16*)  (wsb + OB_WCB);
    f16*   WGB = (f16*)  (wsb + OB_WGB);
    f16*   W5B = (f16*)  (wsb + OB_W5B);
    float* BS  = (float*)(wsb + OB_BS);

    kTrans<<<1152, 256, 0, stream>>>(h0_w, c0_w, W_hh, conv_w, b_ih, b_hh,
                                     WCB, WGB, W5B, BS);
    kHid<<<8192, 256, 0, stream>>>(X, hid_w, hid_b, HID);
    kInit<<<2048, 256, 0, stream>>>(HID, WCB, h0_b, c0_b, HA, CC);
    for (int st = 0; st < 9; ++st) {
        const f16* hin = (st & 1) ? HB : HA;
        f16* hout      = (st & 1) ? HA : HB;
        kFuse<<<2048, 256, 0, stream>>>(hin, WGB, W5B, W_ih, BS, conv_b, CC, hout);
    }
    kPolicy<<<512, 256, 0, stream>>>(HB, pol_w, (float*)d_out);
}

// Round 5
// 951.907 us; speedup vs baseline: 6.3047x; 1.0981x over previous
//
#include <hip/hip_runtime.h>
#include <math.h>

// GPPN fused v3: B=32, L_H=128, MAZE=64, F=5, OUT=16, k=10 (9 LSTM steps)
// h stored fp16 [pix][128]; c fp32 [tile][c][pix-in-tile]; d = h@W5^T fp16 [pix][32]
// computed at the PRODUCER of h (tile-local GEMM, no halo). Consumer stages a
// 12x12x32 d-halo and folds s = sum_tap d[p+delta][tap] into the gates GEMM as
// a K-extension (K=128->160) against a replicated W_ih B-block.

typedef _Float16 f16;
typedef _Float16 f16x8 __attribute__((ext_vector_type(8)));
typedef float    f32x4 __attribute__((ext_vector_type(4)));

#define NB 32
#define HWD 64
#define NPIX (NB*HWD*HWD)   // 131072

// ---- workspace byte offsets
#define OB_HID   ((size_t)0)            // fp16 hid               32 MB
#define OB_CC    ((size_t)33554432)     // fp32 c [blk][128][64]  64 MB
#define OB_HA    ((size_t)100663296)    // fp16 h ping            32 MB
#define OB_HB    ((size_t)134217728)    // fp16 h pong            32 MB
#define OB_DA    ((size_t)167772160)    // fp16 d ping            8 MB
#define OB_DB    ((size_t)176160768)    // fp16 d pong            8 MB
#define OB_WCB   ((size_t)184549376)    // f16 conv3 B-frags      589824 B
#define OB_WGB   ((size_t)185139200)    // f16 W_hh B-frags       131072 B
#define OB_WIB   ((size_t)185270272)    // f16 W_ih replicated    32768 B
#define OB_W5B   ((size_t)185303040)    // f16 W5 B-frags         8192 B
#define OB_BS2   ((size_t)185311232)    // f32 b_ih+b_hh+cb*W_ih  2048 B
#define WS_BYTES ((size_t)185313280)

__device__ __forceinline__ float sigm(float x){ return 1.f/(1.f+__expf(-x)); }
__device__ __forceinline__ float tanhx(float x){ return 1.f - 2.f/(1.f+__expf(2.f*x)); }

// ---------------- one-time weight transforms --------------------------------
// Frag layout (all B-mats): value(frag fb, lane l, j) = W[n][k],
//   n = nt*16 + (l&15), k = kk*32 + (l>>4)*8 + j.
__global__ void kTrans(const float* __restrict__ h0w, const float* __restrict__ c0w,
                       const float* __restrict__ whh, const float* __restrict__ cw5,
                       const float* __restrict__ wih, const float* __restrict__ bih,
                       const float* __restrict__ bhh, const float* __restrict__ cb,
                       f16* __restrict__ wcb, f16* __restrict__ wgb,
                       f16* __restrict__ wib, f16* __restrict__ w5b,
                       float* __restrict__ bs2)
{
    int e = blockIdx.x*256 + threadIdx.x;
    if (e < 294912) {                    // conv3 frags: [tap][nt(16)][kk(4)]; nt<8 h0, nt>=8 c0
        int j = e & 7, l = (e >> 3) & 63, kk = (e >> 9) & 3;
        int nt = (e >> 11) & 15, tap = e >> 15;
        int c = (nt & 7)*16 + (l & 15);
        int k = kk*32 + (l >> 4)*8 + j;
        const float* src = (nt < 8) ? h0w : c0w;
        wcb[e] = (f16)src[((size_t)c*128 + k)*9 + tap];
    }
    if (e < 65536) {                     // W_hh frags [nt(32)][kk(4)]
        int j = e & 7, l = (e >> 3) & 63, fb = e >> 9;
        int nt = fb >> 2, kk = fb & 3;
        int cg = nt*16 + (l & 15), k = kk*32 + (l >> 4)*8 + j;
        wgb[e] = (f16)whh[(size_t)cg*128 + k];
    }
    if (e < 16384) {                     // W_ih replicated ext-block [nt(32)]
        int l = (e >> 3) & 63, nt = e >> 9;
        wib[e] = (f16)wih[nt*16 + (l & 15)];
    }
    if (e < 4096) {                      // W5 frags [nt(2)][kk(4)], taps>=25 zero
        int j = e & 7, l = (e >> 3) & 63, fb = e >> 9;
        int nt = fb >> 2, kk = fb & 3;
        int n = nt*16 + (l & 15), k = kk*32 + (l >> 4)*8 + j;
        w5b[e] = (n < 25) ? (f16)cw5[k*25 + n] : (f16)0.f;
    }
    if (e < 512) bs2[e] = bih[e] + bhh[e] + cb[0]*wih[e];
}

// ---------------- hid = conv3x3(X, hid_w) + hid_b (fp32 math, fp16 out) -----
__global__ __launch_bounds__(256) void kHid(const float* __restrict__ X,
                                            const float* __restrict__ hw,
                                            const float* __restrict__ hb,
                                            f16* __restrict__ hid)
{
    __shared__ float Ws[128*73];
    __shared__ float Xs[6*6*8];
    int t = threadIdx.x;
    int blk = blockIdx.x;
    int b = blk >> 8, ti = (blk >> 4) & 15, tj = blk & 15;
    int i0 = ti*4, j0 = tj*4;
    for (int e = t; e < 9216; e += 256) {
        int c = e/72, q = e - c*72;
        Ws[c*73 + q] = hw[e];
    }
    for (int e = t; e < 288; e += 256) {
        int pos = e >> 3, ci = e & 7;
        int gi = i0 + pos/6 - 1, gj = j0 + pos%6 - 1;
        float v = 0.f;
        if ((unsigned)gi < 64u && (unsigned)gj < 64u)
            v = X[(((size_t)b*8 + ci)*64 + gi)*64 + gj];
        Xs[pos*8 + ci] = v;
    }
    __syncthreads();
    int c = t & 127, ph = t >> 7;
    float bv = hb[c];
    for (int p = ph*8; p < ph*8 + 8; ++p) {
        int pi = p >> 2, pj = p & 3;
        float acc = bv;
        #pragma unroll
        for (int ci = 0; ci < 8; ++ci)
            #pragma unroll
            for (int dy = 0; dy < 3; ++dy)
                #pragma unroll
                for (int dx = 0; dx < 3; ++dx)
                    acc += Xs[((pi+dy)*6 + (pj+dx))*8 + ci] * Ws[c*73 + ci*9 + dy*3 + dx];
        hid[(((size_t)b*64 + i0+pi)*64 + (j0+pj))*128 + c] = (f16)acc;
    }
}

// ---------------- h0 & c0: 9-tap MFMA GEMM + d(h0) tail ---------------------
// block = 8x8 tile, 4 waves; wave wn: nt = wn*4..wn*4+3; wn<2 -> h0, wn>=2 -> c0.
__global__ __launch_bounds__(256,2) void kInit(const f16* __restrict__ hid,
                                               const f16* __restrict__ wcb,
                                               const f16* __restrict__ w5b,
                                               const float* __restrict__ h0b,
                                               const float* __restrict__ c0b,
                                               f16* __restrict__ h0out,
                                               float* __restrict__ cc,
                                               f16* __restrict__ dout)
{
    __shared__ f16 sHalo[100*128];   // 10x10 halo, 25600 B, 16B-chunk XOR-swizzled
    int t = threadIdx.x;
    int blk = blockIdx.x;
    int b = blk >> 6, ti = (blk >> 3) & 7, tj = blk & 7;
    int i0 = ti*8, j0 = tj*8;
    int l = t & 63, wn = t >> 6;

    for (int e = t; e < 1600; e += 256) {
        int pos = e >> 4, ch = e & 15;
        int gi = i0 + pos/10 - 1, gj = j0 + pos%10 - 1;
        f16x8 v = {0,0,0,0,0,0,0,0};
        if ((unsigned)gi < 64u && (unsigned)gj < 64u)
            v = *(const f16x8*)(hid + ((((size_t)b*64 + gi)*64 + gj)*128) + ch*8);
        *(f16x8*)&sHalo[(pos*16 + (ch ^ (pos & 7)))*8] = v;
    }
    __syncthreads();

    f32x4 acc[4][4];   // [mi][q]
    #pragma unroll
    for (int mi = 0; mi < 4; ++mi)
        #pragma unroll
        for (int q = 0; q < 4; ++q) acc[mi][q] = (f32x4){0.f,0.f,0.f,0.f};

    for (int tap = 0; tap < 9; ++tap) {
        int dy = tap/3, dx = tap - dy*3;
        f16x8 a[4][4];
        #pragma unroll
        for (int mi = 0; mi < 4; ++mi) {
            int mrow = mi*16 + (l & 15);
            int pos = ((mrow >> 3) + dy)*10 + (mrow & 7) + dx;
            #pragma unroll
            for (int kk = 0; kk < 4; ++kk)
                a[mi][kk] = *(const f16x8*)&sHalo[(pos*16 + ((kk*4 + (l >> 4)) ^ (pos & 7)))*8];
        }
        #pragma unroll
        for (int q = 0; q < 4; ++q) {
            int nt = wn*4 + q;
            f16x8 bf[4];
            #pragma unroll
            for (int kk = 0; kk < 4; ++kk)
                bf[kk] = *(const f16x8*)(wcb + ((size_t)((tap*16 + nt)*4 + kk)*64 + l)*8);
            #pragma unroll
            for (int mi = 0; mi < 4; ++mi)
                #pragma unroll
                for (int kk = 0; kk < 4; ++kk)
                    acc[mi][q] = __builtin_amdgcn_mfma_f32_16x16x32_f16(a[mi][kk], bf[kk], acc[mi][q], 0, 0, 0);
        }
    }

    __syncthreads();                 // sHalo dead; reuse as sH (h0 tile)
    f16* sH = sHalo;

    int cl = l & 15;
    bool isC = (wn >= 2);
    #pragma unroll
    for (int q = 0; q < 4; ++q) {
        int c = ((wn & 1)*4 + q)*16 + cl;
        float bv = isC ? c0b[c] : h0b[c];
        #pragma unroll
        for (int mi = 0; mi < 4; ++mi) {
            int mbase = mi*16 + (l >> 4)*4;
            if (isC) {
                float4 cv;
                cv.x = acc[mi][q][0] + bv; cv.y = acc[mi][q][1] + bv;
                cv.z = acc[mi][q][2] + bv; cv.w = acc[mi][q][3] + bv;
                *(float4*)(cc + (size_t)blk*8192 + (size_t)c*64 + mbase) = cv;
            } else {
                #pragma unroll
                for (int r = 0; r < 4; ++r) {
                    int m = mbase + r;
                    size_t gp = ((((size_t)b*64 + i0 + (m >> 3))*64 + j0 + (m & 7))*128) + c;
                    f16 hv = (f16)(acc[mi][q][r] + bv);
                    h0out[gp] = hv;
                    sH[(m*16 + ((c >> 3) ^ (m & 7)))*8 + (c & 7)] = hv;
                }
            }
        }
    }
    __syncthreads();

    // d-GEMM tail: wave wn handles M-tile wn. d = h0 . W5^T (N=32, taps>=25 are 0)
    {
        int m0 = wn*16 + (l & 15);
        f16x8 av[4];
        #pragma unroll
        for (int kk = 0; kk < 4; ++kk)
            av[kk] = *(const f16x8*)&sH[(m0*16 + ((kk*4 + (l >> 4)) ^ (m0 & 7)))*8];
        #pragma unroll
        for (int nt = 0; nt < 2; ++nt) {
            f32x4 dc = {0.f,0.f,0.f,0.f};
            #pragma unroll
            for (int kk = 0; kk < 4; ++kk)
                dc = __builtin_amdgcn_mfma_f32_16x16x32_f16(av[kk],
                        *(const f16x8*)(w5b + ((size_t)((nt*4 + kk)*64 + l))*8), dc, 0, 0, 0);
            #pragma unroll
            for (int r = 0; r < 4; ++r) {
                int mm = wn*16 + (l >> 4)*4 + r;
                size_t gp = ((((size_t)b*64 + i0 + (mm >> 3))*64 + j0 + (mm & 7))*32) + nt*16 + (l & 15);
                dout[gp] = (f16)dc[r];
            }
        }
    }
}

// ---------------- fused LSTM step v3 ----------------------------------------
// gates = h.Whh^T + s.Wih^T + bias, K-ext trick: s via d-halo as K=[128..160).
// block = 8x8 tile, 4 waves; wave w: wn=w>>1 (c-half), wm=w&1 (M-tile parity).
__global__ __launch_bounds__(256,4) void kFuse(const f16* __restrict__ hin,
                                               const f16* __restrict__ din,
                                               const f16* __restrict__ wgb,
                                               const f16* __restrict__ wib,
                                               const f16* __restrict__ w5b,
                                               const float* __restrict__ bs2,
                                               float* __restrict__ cc,
                                               f16* __restrict__ hout,
                                               f16* __restrict__ dout)
{
    __shared__ f16 sDH[144*32];      // 12x12 d-halo, linear, 9216 B
    __shared__ f16 sH[64*128];       // h_new tile for d-GEMM, swizzled, 16384 B
    int t = threadIdx.x;
    int blk = blockIdx.x;
    int b = blk >> 6, ti = (blk >> 3) & 7, tj = blk & 7;
    int i0 = ti*8, j0 = tj*8;
    int l = t & 63, w = t >> 6;
    int wn = w >> 1, wm = w & 1;
    int cl = l & 15;

    // gates A-frags straight from global h (own tile, no halo)
    f16x8 a[2][4];
    #pragma unroll
    for (int mi = 0; mi < 2; ++mi) {
        int m = (wm + mi*2)*16 + (l & 15);
        size_t gp = (((size_t)b*64 + i0 + (m >> 3))*64 + j0 + (m & 7))*128;
        #pragma unroll
        for (int kk = 0; kk < 4; ++kk)
            a[mi][kk] = *(const f16x8*)(hin + gp + kk*32 + (l >> 4)*8);
    }
    // stage 12x12 d-halo (zero-padded)
    for (int e = t; e < 576; e += 256) {
        int pos = e >> 2, ch = e & 3;
        int gi = i0 + pos/12 - 2, gj = j0 + pos%12 - 2;
        f16x8 v = {0,0,0,0,0,0,0,0};
        if ((unsigned)gi < 64u && (unsigned)gj < 64u)
            v = *(const f16x8*)(din + (((size_t)b*64 + gi)*64 + gj)*32 + ch*8);
        *(f16x8*)&sDH[pos*32 + ch*8] = v;
    }
    __syncthreads();

    // K-ext A-frags: dh[m][k'] = d[p+delta(k')][k'], k' = (l>>4)*8+j
    f16x8 adh[2];
    #pragma unroll
    for (int mi = 0; mi < 2; ++mi) {
        int m = (wm + mi*2)*16 + (l & 15);
        int pi = m >> 3, pj = m & 7;
        f16 tmp[8];
        #pragma unroll
        for (int j = 0; j < 8; ++j) {
            int kp = (l >> 4)*8 + j;
            int kpc = (kp < 25) ? kp : 0;
            int ty = kpc/5, tx = kpc - ty*5;
            f16 v = sDH[((pi + ty)*12 + (pj + tx))*32 + kpc];
            tmp[j] = (kp < 25) ? v : (f16)0.f;
        }
        adh[mi] = *(f16x8*)tmp;
    }

    bool doD = (dout != nullptr);
    #pragma unroll
    for (int q = 0; q < 4; ++q) {
        f32x4 acc2[2][4];            // [mi][gate]
        #pragma unroll
        for (int mi = 0; mi < 2; ++mi)
            #pragma unroll
            for (int g = 0; g < 4; ++g) acc2[mi][g] = (f32x4){0.f,0.f,0.f,0.f};
        #pragma unroll
        for (int g = 0; g < 4; ++g) {
            int nt = g*8 + wn*4 + q;
            #pragma unroll
            for (int kk = 0; kk < 4; ++kk) {
                f16x8 bf = *(const f16x8*)(wgb + ((size_t)((nt*4 + kk)*64 + l))*8);
                #pragma unroll
                for (int mi = 0; mi < 2; ++mi)
                    acc2[mi][g] = __builtin_amdgcn_mfma_f32_16x16x32_f16(a[mi][kk], bf, acc2[mi][g], 0, 0, 0);
            }
            f16x8 be = *(const f16x8*)(wib + ((size_t)(nt*64 + l))*8);
            #pragma unroll
            for (int mi = 0; mi < 2; ++mi)
                acc2[mi][g] = __builtin_amdgcn_mfma_f32_16x16x32_f16(adh[mi], be, acc2[mi][g], 0, 0, 0);
        }
        // epilogue for this channel-quad
        int c = (wn*4 + q)*16 + cl;
        float bi = bs2[c], bff = bs2[128 + c], bg = bs2[256 + c], bo = bs2[384 + c];
        #pragma unroll
        for (int mi = 0; mi < 2; ++mi) {
            int mbase = (wm + mi*2)*16 + (l >> 4)*4;
            size_t cbase = (size_t)blk*8192 + (size_t)c*64 + mbase;
            float4 cold = *(const float4*)(cc + cbase);
            const float* cp = (const float*)&cold;
            float cn[4], hn[4];
            #pragma unroll
            for (int r = 0; r < 4; ++r) {
                float vi = acc2[mi][0][r] + bi;
                float vf = acc2[mi][1][r] + bff;
                float vg = acc2[mi][2][r] + bg;
                float vo = acc2[mi][3][r] + bo;
                float cv = sigm(vf)*cp[r] + sigm(vi)*tanhx(vg);
                cn[r] = cv;
                hn[r] = sigm(vo)*tanhx(cv);
            }
            *(float4*)(cc + cbase) = make_float4(cn[0], cn[1], cn[2], cn[3]);
            #pragma unroll
            for (int r = 0; r < 4; ++r) {
                int m = mbase + r;
                size_t gp = ((((size_t)b*64 + i0 + (m >> 3))*64 + j0 + (m & 7))*128) + c;
                f16 hv = (f16)hn[r];
                hout[gp] = hv;
                if (doD) sH[(m*16 + ((c >> 3) ^ (m & 7)))*8 + (c & 7)] = hv;
            }
        }
    }

    if (doD) {
        __syncthreads();
        // d-GEMM: wave w -> M-tile w
        int m0 = w*16 + (l & 15);
        f16x8 av[4];
        #pragma unroll
        for (int kk = 0; kk < 4; ++kk)
            av[kk] = *(const f16x8*)&sH[(m0*16 + ((kk*4 + (l >> 4)) ^ (m0 & 7)))*8];
        #pragma unroll
        for (int nt = 0; nt < 2; ++nt) {
            f32x4 dc = {0.f,0.f,0.f,0.f};
            #pragma unroll
            for (int kk = 0; kk < 4; ++kk)
                dc = __builtin_amdgcn_mfma_f32_16x16x32_f16(av[kk],
                        *(const f16x8*)(w5b + ((size_t)((nt*4 + kk)*64 + l))*8), dc, 0, 0, 0);
            #pragma unroll
            for (int r = 0; r < 4; ++r) {
                int mm = w*16 + (l >> 4)*4 + r;
                size_t gp = ((((size_t)b*64 + i0 + (mm >> 3))*64 + j0 + (mm & 7))*32) + nt*16 + (l & 15);
                dout[gp] = (f16)dc[r];
            }
        }
    }
}

// ---------------- policy 1x1 conv (fp16 h in, fp32 out) ---------------------
__global__ __launch_bounds__(256) void kPolicy(const f16* __restrict__ h,
                                               const float* __restrict__ pw,
                                               float* __restrict__ out)
{
    __shared__ float Ps[16*128];
    int t = threadIdx.x;
    for (int e = t; e < 2048; e += 256) Ps[e] = pw[e];
    __syncthreads();
    size_t pid = (size_t)blockIdx.x*256 + t;
    int b = (int)(pid >> 12), rem = (int)(pid & 4095);
    float acc[16];
    #pragma unroll
    for (int o = 0; o < 16; ++o) acc[o] = 0.f;
    const f16x8* hb8 = (const f16x8*)(h + pid*128);
    #pragma unroll 2
    for (int k8 = 0; k8 < 16; ++k8) {
        f16x8 hv = hb8[k8];
        float hf[8];
        #pragma unroll
        for (int e = 0; e < 8; ++e) hf[e] = (float)hv[e];
        #pragma unroll
        for (int o = 0; o < 16; ++o) {
            float4 w0 = *(const float4*)&Ps[o*128 + k8*8];
            float4 w1 = *(const float4*)&Ps[o*128 + k8*8 + 4];
            acc[o] += hf[0]*w0.x + hf[1]*w0.y + hf[2]*w0.z + hf[3]*w0.w
                    + hf[4]*w1.x + hf[5]*w1.y + hf[6]*w1.z + hf[7]*w1.w;
        }
    }
    #pragma unroll
    for (int o = 0; o < 16; ++o)
        out[((size_t)b*16 + o)*4096 + rem] = acc[o];
}

extern "C" void kernel_launch(void* const* d_in, const int* in_sizes, int n_in,
                              void* d_out, int out_size, void* d_ws, size_t ws_size,
                              hipStream_t stream) {
    const float* X      = (const float*)d_in[0];
    const float* hid_w  = (const float*)d_in[1];
    const float* hid_b  = (const float*)d_in[2];
    const float* h0_w   = (const float*)d_in[3];
    const float* h0_b   = (const float*)d_in[4];
    const float* c0_w   = (const float*)d_in[5];
    const float* c0_b   = (const float*)d_in[6];
    const float* conv_w = (const float*)d_in[7];
    const float* conv_b = (const float*)d_in[8];
    const float* W_ih   = (const float*)d_in[9];
    const float* W_hh   = (const float*)d_in[10];
    const float* b_ih   = (const float*)d_in[11];
    const float* b_hh   = (const float*)d_in[12];
    const float* pol_w  = (const float*)d_in[13];
    // d_in[14] = k (=10); steps = k-1 = 9 hard-coded

    if (ws_size < WS_BYTES) return;   // fail-visible guard

    char* wsb = (char*)d_ws;
    f16*   HID = (f16*)  (wsb + OB_HID);
    float* CC  = (float*)(wsb + OB_CC);
    f16*   HA  = (f16*)  (wsb + OB_HA);
    f16*   HB  = (f16*)  (wsb + OB_HB);
    f16*   DA  = (f16*)  (wsb + OB_DA);
    f16*   DB  = (f16*)  (wsb + OB_DB);
    f16*   WCB = (f16*)  (wsb + OB_WCB);
    f16*   WGB = (f16*)  (wsb + OB_WGB);
    f16*   WIB = (f16*)  (wsb + OB_WIB);
    f16*   W5B = (f16*)  (wsb + OB_W5B);
    float* BS2 = (float*)(wsb + OB_BS2);

    kTrans<<<1152, 256, 0, stream>>>(h0_w, c0_w, W_hh, conv_w, W_ih, b_ih, b_hh, conv_b,
                                     WCB, WGB, WIB, W5B, BS2);
    kHid<<<8192, 256, 0, stream>>>(X, hid_w, hid_b, HID);
    kInit<<<2048, 256, 0, stream>>>(HID, WCB, W5B, h0_b, c0_b, HA, CC, DA);
    for (int st = 0; st < 9; ++st) {
        const f16* hin = (st & 1) ? HB : HA;
        const f16* din = (st & 1) ? DB : DA;
        f16* hout      = (st & 1) ? HA : HB;
        f16* dout      = (st & 1) ? DA : DB;
        if (st == 8) dout = nullptr;   // last step: d unused
        kFuse<<<2048, 256, 0, stream>>>(hin, din, WGB, WIB, W5B, BS2, CC, hout, dout);
    }
    kPolicy<<<512, 256, 0, stream>>>(HB, pol_w, (float*)d_out);
}

// Round 6
// 900.597 us; speedup vs baseline: 6.6639x; 1.0570x over previous
//
#include <hip/hip_runtime.h>
#include <math.h>

// GPPN fused v4: B=32, L_H=128, MAZE=64, F=5, OUT=16, k=10 (9 LSTM steps)
// h fp16 [pix][128]; c fp32 [tile][c][pix]; d = h@W5^T fp16 [pix][32] at producer.
// hid is never materialized in HBM: kInit computes it in-LDS from a 12x12x8 X halo
// via a K=96 MFMA GEMM (taps 9..11 zero in B), then runs the 9-tap h0/c0 GEMM.

typedef _Float16 f16;
typedef _Float16 f16x8 __attribute__((ext_vector_type(8)));
typedef float    f32x4 __attribute__((ext_vector_type(4)));

#define NB 32
#define HWD 64
#define NPIX (NB*HWD*HWD)   // 131072

// ---- workspace byte offsets
#define OB_CC    ((size_t)0)            // fp32 c [blk][128][64]  64 MB
#define OB_HA    ((size_t)67108864)     // fp16 h ping            32 MB
#define OB_HB    ((size_t)100663296)    // fp16 h pong            32 MB
#define OB_DA    ((size_t)134217728)    // fp16 d ping            8 MB
#define OB_DB    ((size_t)142606336)    // fp16 d pong            8 MB
#define OB_WCB   ((size_t)150994944)    // f16 conv3 B-frags      589824 B
#define OB_WGB   ((size_t)151584768)    // f16 W_hh B-frags       131072 B
#define OB_WIB   ((size_t)151715840)    // f16 W_ih replicated    32768 B
#define OB_W5B   ((size_t)151748608)    // f16 W5 B-frags         8192 B
#define OB_WHB   ((size_t)151756800)    // f16 hid_w B-frags K=96 24576 B
#define OB_BS2   ((size_t)151781376)    // f32 b_ih+b_hh+cb*W_ih  2048 B
#define WS_BYTES ((size_t)151783424)

__device__ __forceinline__ float sigm(float x){ return 1.f/(1.f+__expf(-x)); }
__device__ __forceinline__ float tanhx(float x){ return 1.f - 2.f/(1.f+__expf(2.f*x)); }

// ---------------- one-time weight transforms --------------------------------
// Frag layout (all B-mats): value(frag fb, lane l, j) = W[n][k],
//   n = nt*16 + (l&15), k = kk*32 + (l>>4)*8 + j.
__global__ void kTrans(const float* __restrict__ h0w, const float* __restrict__ c0w,
                       const float* __restrict__ whh, const float* __restrict__ cw5,
                       const float* __restrict__ wih, const float* __restrict__ hw,
                       const float* __restrict__ bih, const float* __restrict__ bhh,
                       const float* __restrict__ cb,
                       f16* __restrict__ wcb, f16* __restrict__ wgb,
                       f16* __restrict__ wib, f16* __restrict__ w5b,
                       f16* __restrict__ whb, float* __restrict__ bs2)
{
    int e = blockIdx.x*256 + threadIdx.x;
    if (e < 294912) {                    // conv3 frags: [tap][nt(16)][kk(4)]; nt<8 h0, nt>=8 c0
        int j = e & 7, l = (e >> 3) & 63, kk = (e >> 9) & 3;
        int nt = (e >> 11) & 15, tap = e >> 15;
        int c = (nt & 7)*16 + (l & 15);
        int k = kk*32 + (l >> 4)*8 + j;
        const float* src = (nt < 8) ? h0w : c0w;
        wcb[e] = (f16)src[((size_t)c*128 + k)*9 + tap];
    }
    if (e < 65536) {                     // W_hh frags [nt(32)][kk(4)]
        int j = e & 7, l = (e >> 3) & 63, fb = e >> 9;
        int nt = fb >> 2, kk = fb & 3;
        int cg = nt*16 + (l & 15), k = kk*32 + (l >> 4)*8 + j;
        wgb[e] = (f16)whh[(size_t)cg*128 + k];
    }
    if (e < 16384) {                     // W_ih replicated ext-block [nt(32)]
        int l = (e >> 3) & 63, nt = e >> 9;
        wib[e] = (f16)wih[nt*16 + (l & 15)];
    }
    if (e < 12288) {                     // hid_w frags [nt(8)][kk(3)], K=96 (taps 9..11 zero)
        int j = e & 7, l = (e >> 3) & 63, fb = e >> 9;
        int nt = fb/3, kk = fb - nt*3;
        int c = nt*16 + (l & 15), k = kk*32 + (l >> 4)*8 + j;
        whb[e] = (k < 72) ? (f16)hw[(size_t)c*72 + (k & 7)*9 + (k >> 3)] : (f16)0.f;
    }
    if (e < 4096) {                      // W5 frags [nt(2)][kk(4)], taps>=25 zero
        int j = e & 7, l = (e >> 3) & 63, fb = e >> 9;
        int nt = fb >> 2, kk = fb & 3;
        int n = nt*16 + (l & 15), k = kk*32 + (l >> 4)*8 + j;
        w5b[e] = (n < 25) ? (f16)cw5[k*25 + n] : (f16)0.f;
    }
    if (e < 512) bs2[e] = bih[e] + bhh[e] + cb[0]*wih[e];
}

// ---------------- kInit: X -> hid (in LDS) -> h0,c0 (+d tail) ---------------
// block = 8x8 tile, 4 waves.
__global__ __launch_bounds__(256,2) void kInit(const float* __restrict__ X,
                                               const f16* __restrict__ whb,
                                               const float* __restrict__ hidb,
                                               const f16* __restrict__ wcb,
                                               const f16* __restrict__ w5b,
                                               const float* __restrict__ h0b,
                                               const float* __restrict__ c0b,
                                               f16* __restrict__ h0out,
                                               float* __restrict__ cc,
                                               f16* __restrict__ dout)
{
    __shared__ f16 sX[1536];         // 12x12x8 X halo (f16), zero-padded + zero tail
    __shared__ f16 sHalo[100*128];   // hid 10x10 halo, 16B-chunk XOR-swizzled
    int t = threadIdx.x;
    int blk = blockIdx.x;
    int b = blk >> 6, ti = (blk >> 3) & 7, tj = blk & 7;
    int i0 = ti*8, j0 = tj*8;
    int l = t & 63, wn = t >> 6;

    // ---- stage X halo (fp32 -> f16)
    for (int e = t; e < 1536; e += 256) {
        if (e < 1152) {
            int ci = e/144, pos = e - ci*144;
            int gi = i0 + pos/12 - 2, gj = j0 + pos%12 - 2;
            float xv = 0.f;
            if ((unsigned)gi < 64u && (unsigned)gj < 64u)
                xv = X[(((size_t)b*8 + ci)*64 + gi)*64 + gj];
            sX[pos*8 + ci] = (f16)xv;
        } else {
            sX[e] = (f16)0.f;
        }
    }
    __syncthreads();

    // ---- hid GEMM: M=100(pad112) x N=128 x K=96 -> sHalo (swizzled, +hid_b)
    for (int mt = wn; mt < 7; mt += 4) {
        int m = mt*16 + (l & 15);
        int pi = m/10, pj = m - pi*10;
        f16x8 ax[3];
        #pragma unroll
        for (int kk = 0; kk < 3; ++kk) {
            int tap = kk*4 + (l >> 4);
            int dy = tap/3, dx = tap - dy*3;
            ax[kk] = *(const f16x8*)&sX[((pi + dy)*12 + (pj + dx))*8];
        }
        #pragma unroll
        for (int nt = 0; nt < 8; ++nt) {
            f32x4 hc = {0.f,0.f,0.f,0.f};
            #pragma unroll
            for (int kk = 0; kk < 3; ++kk)
                hc = __builtin_amdgcn_mfma_f32_16x16x32_f16(ax[kk],
                        *(const f16x8*)(whb + ((size_t)(nt*3 + kk)*64 + l)*8), hc, 0, 0, 0);
            int c = nt*16 + (l & 15);
            float bv = hidb[c];
            #pragma unroll
            for (int r = 0; r < 4; ++r) {
                int m2 = mt*16 + (l >> 4)*4 + r;
                if (m2 < 100) {
                    int pi2 = m2/10, pj2 = m2 - pi2*10;
                    int gi = i0 + pi2 - 1, gj = j0 + pj2 - 1;
                    bool inb = ((unsigned)gi < 64u && (unsigned)gj < 64u);
                    sHalo[(m2*16 + ((c >> 3) ^ (m2 & 7)))*8 + (c & 7)] =
                        inb ? (f16)(hc[r] + bv) : (f16)0.f;
                }
            }
        }
    }
    __syncthreads();

    // ---- h0/c0 9-tap GEMM (A from sHalo)
    f32x4 acc[4][4];   // [mi][q]
    #pragma unroll
    for (int mi = 0; mi < 4; ++mi)
        #pragma unroll
        for (int q = 0; q < 4; ++q) acc[mi][q] = (f32x4){0.f,0.f,0.f,0.f};

    for (int tap = 0; tap < 9; ++tap) {
        int dy = tap/3, dx = tap - dy*3;
        f16x8 a[4][4];
        #pragma unroll
        for (int mi = 0; mi < 4; ++mi) {
            int mrow = mi*16 + (l & 15);
            int pos = ((mrow >> 3) + dy)*10 + (mrow & 7) + dx;
            #pragma unroll
            for (int kk = 0; kk < 4; ++kk)
                a[mi][kk] = *(const f16x8*)&sHalo[(pos*16 + ((kk*4 + (l >> 4)) ^ (pos & 7)))*8];
        }
        #pragma unroll
        for (int q = 0; q < 4; ++q) {
            int nt = wn*4 + q;
            f16x8 bf[4];
            #pragma unroll
            for (int kk = 0; kk < 4; ++kk)
                bf[kk] = *(const f16x8*)(wcb + ((size_t)((tap*16 + nt)*4 + kk)*64 + l)*8);
            #pragma unroll
            for (int mi = 0; mi < 4; ++mi)
                #pragma unroll
                for (int kk = 0; kk < 4; ++kk)
                    acc[mi][q] = __builtin_amdgcn_mfma_f32_16x16x32_f16(a[mi][kk], bf[kk], acc[mi][q], 0, 0, 0);
        }
    }

    __syncthreads();                 // sHalo dead; reuse as sH (h0 8x8 tile)
    f16* sH = sHalo;

    int cl = l & 15;
    bool isC = (wn >= 2);
    #pragma unroll
    for (int q = 0; q < 4; ++q) {
        int c = ((wn & 1)*4 + q)*16 + cl;
        float bv = isC ? c0b[c] : h0b[c];
        #pragma unroll
        for (int mi = 0; mi < 4; ++mi) {
            int mbase = mi*16 + (l >> 4)*4;
            if (isC) {
                float4 cv;
                cv.x = acc[mi][q][0] + bv; cv.y = acc[mi][q][1] + bv;
                cv.z = acc[mi][q][2] + bv; cv.w = acc[mi][q][3] + bv;
                *(float4*)(cc + (size_t)blk*8192 + (size_t)c*64 + mbase) = cv;
            } else {
                #pragma unroll
                for (int r = 0; r < 4; ++r) {
                    int m = mbase + r;
                    sH[(m*16 + ((c >> 3) ^ (m & 7)))*8 + (c & 7)] = (f16)(acc[mi][q][r] + bv);
                }
            }
        }
    }
    __syncthreads();

    // ---- d tail: d = h0 . W5^T (wave wn -> M-tile wn)
    {
        int m0 = wn*16 + (l & 15);
        f16x8 av[4];
        #pragma unroll
        for (int kk = 0; kk < 4; ++kk)
            av[kk] = *(const f16x8*)&sH[(m0*16 + ((kk*4 + (l >> 4)) ^ (m0 & 7)))*8];
        #pragma unroll
        for (int nt = 0; nt < 2; ++nt) {
            f32x4 dc = {0.f,0.f,0.f,0.f};
            #pragma unroll
            for (int kk = 0; kk < 4; ++kk)
                dc = __builtin_amdgcn_mfma_f32_16x16x32_f16(av[kk],
                        *(const f16x8*)(w5b + ((size_t)((nt*4 + kk)*64 + l))*8), dc, 0, 0, 0);
            #pragma unroll
            for (int r = 0; r < 4; ++r) {
                int mm = wn*16 + (l >> 4)*4 + r;
                size_t gp = ((((size_t)b*64 + i0 + (mm >> 3))*64 + j0 + (mm & 7))*32) + nt*16 + (l & 15);
                dout[gp] = (f16)dc[r];
            }
        }
    }
    // ---- vectorized h0 store from sH
    for (int e = t; e < 1024; e += 256) {
        int pos = e >> 4, ch = e & 15;
        f16x8 v = *(const f16x8*)&sH[(pos*16 + (ch ^ (pos & 7)))*8];
        *(f16x8*)(h0out + ((((size_t)b*64 + i0 + (pos >> 3))*64 + j0 + (pos & 7))*128) + ch*8) = v;
    }
}

// ---------------- fused LSTM step v4 ----------------------------------------
// gates = h.Whh^T + s.Wih^T + bias; s via d-halo K-extension (K=128->160).
__global__ __launch_bounds__(256,4) void kFuse(const f16* __restrict__ hin,
                                               const f16* __restrict__ din,
                                               const f16* __restrict__ wgb,
                                               const f16* __restrict__ wib,
                                               const f16* __restrict__ w5b,
                                               const float* __restrict__ bs2,
                                               float* __restrict__ cc,
                                               f16* __restrict__ hout,
                                               f16* __restrict__ dout)
{
    __shared__ f16 sDH[144*32];      // 12x12 d-halo, linear, 9216 B
    __shared__ f16 sH[64*128];       // h_new tile, swizzled, 16384 B
    int t = threadIdx.x;
    int blk = blockIdx.x;
    int b = blk >> 6, ti = (blk >> 3) & 7, tj = blk & 7;
    int i0 = ti*8, j0 = tj*8;
    int l = t & 63, w = t >> 6;
    int wn = w >> 1, wm = w & 1;
    int cl = l & 15;

    // gates A-frags straight from global h (own tile)
    f16x8 a[2][4];
    #pragma unroll
    for (int mi = 0; mi < 2; ++mi) {
        int m = (wm + mi*2)*16 + (l & 15);
        size_t gp = (((size_t)b*64 + i0 + (m >> 3))*64 + j0 + (m & 7))*128;
        #pragma unroll
        for (int kk = 0; kk < 4; ++kk)
            a[mi][kk] = *(const f16x8*)(hin + gp + kk*32 + (l >> 4)*8);
    }
    // hoisted c loads (latency overlapped with MFMA section)
    float4 coldv[4][2];
    #pragma unroll
    for (int q = 0; q < 4; ++q)
        #pragma unroll
        for (int mi = 0; mi < 2; ++mi) {
            int c = (wn*4 + q)*16 + cl;
            int mbase = (wm + mi*2)*16 + (l >> 4)*4;
            coldv[q][mi] = *(const float4*)(cc + (size_t)blk*8192 + (size_t)c*64 + mbase);
        }
    // stage 12x12 d-halo (zero-padded)
    for (int e = t; e < 576; e += 256) {
        int pos = e >> 2, ch = e & 3;
        int gi = i0 + pos/12 - 2, gj = j0 + pos%12 - 2;
        f16x8 v = {0,0,0,0,0,0,0,0};
        if ((unsigned)gi < 64u && (unsigned)gj < 64u)
            v = *(const f16x8*)(din + (((size_t)b*64 + gi)*64 + gj)*32 + ch*8);
        *(f16x8*)&sDH[pos*32 + ch*8] = v;
    }
    __syncthreads();

    // K-ext A-frags: dh[m][k'] = d[p+delta(k')][k']
    f16x8 adh[2];
    #pragma unroll
    for (int mi = 0; mi < 2; ++mi) {
        int m = (wm + mi*2)*16 + (l & 15);
        int pi = m >> 3, pj = m & 7;
        f16 tmp[8];
        #pragma unroll
        for (int j = 0; j < 8; ++j) {
            int kp = (l >> 4)*8 + j;
            int kpc = (kp < 25) ? kp : 0;
            int ty = kpc/5, tx = kpc - ty*5;
            f16 v = sDH[((pi + ty)*12 + (pj + tx))*32 + kpc];
            tmp[j] = (kp < 25) ? v : (f16)0.f;
        }
        adh[mi] = *(f16x8*)tmp;
    }

    bool doD = (dout != nullptr);
    #pragma unroll
    for (int q = 0; q < 4; ++q) {
        f32x4 acc2[2][4];            // [mi][gate]
        #pragma unroll
        for (int mi = 0; mi < 2; ++mi)
            #pragma unroll
            for (int g = 0; g < 4; ++g) acc2[mi][g] = (f32x4){0.f,0.f,0.f,0.f};
        #pragma unroll
        for (int g = 0; g < 4; ++g) {
            int nt = g*8 + wn*4 + q;
            #pragma unroll
            for (int kk = 0; kk < 4; ++kk) {
                f16x8 bf = *(const f16x8*)(wgb + ((size_t)((nt*4 + kk)*64 + l))*8);
                #pragma unroll
                for (int mi = 0; mi < 2; ++mi)
                    acc2[mi][g] = __builtin_amdgcn_mfma_f32_16x16x32_f16(a[mi][kk], bf, acc2[mi][g], 0, 0, 0);
            }
            f16x8 be = *(const f16x8*)(wib + ((size_t)(nt*64 + l))*8);
            #pragma unroll
            for (int mi = 0; mi < 2; ++mi)
                acc2[mi][g] = __builtin_amdgcn_mfma_f32_16x16x32_f16(adh[mi], be, acc2[mi][g], 0, 0, 0);
        }
        // epilogue for this channel-quad
        int c = (wn*4 + q)*16 + cl;
        float bi = bs2[c], bff = bs2[128 + c], bg = bs2[256 + c], bo = bs2[384 + c];
        #pragma unroll
        for (int mi = 0; mi < 2; ++mi) {
            int mbase = (wm + mi*2)*16 + (l >> 4)*4;
            size_t cbase = (size_t)blk*8192 + (size_t)c*64 + mbase;
            const float* cp = (const float*)&coldv[q][mi];
            float cn[4], hn[4];
            #pragma unroll
            for (int r = 0; r < 4; ++r) {
                float vi = acc2[mi][0][r] + bi;
                float vf = acc2[mi][1][r] + bff;
                float vg = acc2[mi][2][r] + bg;
                float vo = acc2[mi][3][r] + bo;
                float cv = sigm(vf)*cp[r] + sigm(vi)*tanhx(vg);
                cn[r] = cv;
                hn[r] = sigm(vo)*tanhx(cv);
            }
            *(float4*)(cc + cbase) = make_float4(cn[0], cn[1], cn[2], cn[3]);
            #pragma unroll
            for (int r = 0; r < 4; ++r) {
                int m = mbase + r;
                sH[(m*16 + ((c >> 3) ^ (m & 7)))*8 + (c & 7)] = (f16)hn[r];
            }
        }
    }

    __syncthreads();
    if (doD) {
        // d-GEMM: wave w -> M-tile w
        int m0 = w*16 + (l & 15);
        f16x8 av[4];
        #pragma unroll
        for (int kk = 0; kk < 4; ++kk)
            av[kk] = *(const f16x8*)&sH[(m0*16 + ((kk*4 + (l >> 4)) ^ (m0 & 7)))*8];
        #pragma unroll
        for (int nt = 0; nt < 2; ++nt) {
            f32x4 dc = {0.f,0.f,0.f,0.f};
            #pragma unroll
            for (int kk = 0; kk < 4; ++kk)
                dc = __builtin_amdgcn_mfma_f32_16x16x32_f16(av[kk],
                        *(const f16x8*)(w5b + ((size_t)((nt*4 + kk)*64 + l))*8), dc, 0, 0, 0);
            #pragma unroll
            for (int r = 0; r < 4; ++r) {
                int mm = w*16 + (l >> 4)*4 + r;
                size_t gp = ((((size_t)b*64 + i0 + (mm >> 3))*64 + j0 + (mm & 7))*32) + nt*16 + (l & 15);
                dout[gp] = (f16)dc[r];
            }
        }
    }
    // vectorized h store from sH
    for (int e = t; e < 1024; e += 256) {
        int pos = e >> 4, ch = e & 15;
        f16x8 v = *(const f16x8*)&sH[(pos*16 + (ch ^ (pos & 7)))*8];
        *(f16x8*)(hout + ((((size_t)b*64 + i0 + (pos >> 3))*64 + j0 + (pos & 7))*128) + ch*8) = v;
    }
}

// ---------------- policy 1x1 conv (fp16 h in, fp32 out) ---------------------
__global__ __launch_bounds__(256) void kPolicy(const f16* __restrict__ h,
                                               const float* __restrict__ pw,
                                               float* __restrict__ out)
{
    __shared__ float Ps[16*128];
    int t = threadIdx.x;
    for (int e = t; e < 2048; e += 256) Ps[e] = pw[e];
    __syncthreads();
    size_t pid = (size_t)blockIdx.x*256 + t;
    int b = (int)(pid >> 12), rem = (int)(pid & 4095);
    float acc[16];
    #pragma unroll
    for (int o = 0; o < 16; ++o) acc[o] = 0.f;
    const f16x8* hb8 = (const f16x8*)(h + pid*128);
    #pragma unroll 2
    for (int k8 = 0; k8 < 16; ++k8) {
        f16x8 hv = hb8[k8];
        float hf[8];
        #pragma unroll
        for (int e = 0; e < 8; ++e) hf[e] = (float)hv[e];
        #pragma unroll
        for (int o = 0; o < 16; ++o) {
            float4 w0 = *(const float4*)&Ps[o*128 + k8*8];
            float4 w1 = *(const float4*)&Ps[o*128 + k8*8 + 4];
            acc[o] += hf[0]*w0.x + hf[1]*w0.y + hf[2]*w0.z + hf[3]*w0.w
                    + hf[4]*w1.x + hf[5]*w1.y + hf[6]*w1.z + hf[7]*w1.w;
        }
    }
    #pragma unroll
    for (int o = 0; o < 16; ++o)
        out[((size_t)b*16 + o)*4096 + rem] = acc[o];
}

extern "C" void kernel_launch(void* const* d_in, const int* in_sizes, int n_in,
                              void* d_out, int out_size, void* d_ws, size_t ws_size,
                              hipStream_t stream) {
    const float* X      = (const float*)d_in[0];
    const float* hid_w  = (const float*)d_in[1];
    const float* hid_b  = (const float*)d_in[2];
    const float* h0_w   = (const float*)d_in[3];
    const float* h0_b   = (const float*)d_in[4];
    const float* c0_w   = (const float*)d_in[5];
    const float* c0_b   = (const float*)d_in[6];
    const float* conv_w = (const float*)d_in[7];
    const float* conv_b = (const float*)d_in[8];
    const float* W_ih   = (const float*)d_in[9];
    const float* W_hh   = (const float*)d_in[10];
    const float* b_ih   = (const float*)d_in[11];
    const float* b_hh   = (const float*)d_in[12];
    const float* pol_w  = (const float*)d_in[13];
    // d_in[14] = k (=10); steps = k-1 = 9 hard-coded

    if (ws_size < WS_BYTES) return;   // fail-visible guard

    char* wsb = (char*)d_ws;
    float* CC  = (float*)(wsb + OB_CC);
    f16*   HA  = (f16*)  (wsb + OB_HA);
    f16*   HB  = (f16*)  (wsb + OB_HB);
    f16*   DA  = (f16*)  (wsb + OB_DA);
    f16*   DB  = (f16*)  (wsb + OB_DB);
    f16*   WCB = (f16*)  (wsb + OB_WCB);
    f16*   WGB = (f16*)  (wsb + OB_WGB);
    f16*   WIB = (f16*)  (wsb + OB_WIB);
    f16*   W5B = (f16*)  (wsb + OB_W5B);
    f16*   WHB = (f16*)  (wsb + OB_WHB);
    float* BS2 = (float*)(wsb + OB_BS2);

    kTrans<<<1152, 256, 0, stream>>>(h0_w, c0_w, W_hh, conv_w, W_ih, hid_w,
                                     b_ih, b_hh, conv_b,
                                     WCB, WGB, WIB, W5B, WHB, BS2);
    kInit<<<2048, 256, 0, stream>>>(X, WHB, hid_b, WCB, W5B, h0_b, c0_b, HA, CC, DA);
    for (int st = 0; st < 9; ++st) {
        const f16* hin = (st & 1) ? HB : HA;
        const f16* din = (st & 1) ? DB : DA;
        f16* hout      = (st & 1) ? HA : HB;
        f16* dout      = (st & 1) ? DA : DB;
        if (st == 8) dout = nullptr;   // last step: d unused
        kFuse<<<2048, 256, 0, stream>>>(hin, din, WGB, WIB, W5B, BS2, CC, hout, dout);
    }
    kPolicy<<<512, 256, 0, stream>>>(HB, pol_w, (float*)d_out);
}